// Round 1
// baseline (429.693 us; speedup 1.0000x reference)
//
#include <hip/hip_runtime.h>
#include <hip/hip_bf16.h>
#include <cstdint>
#include <cstddef>

#define HIDDEN 768
#define HEADS 12
#define HD 64
#define SEQ 4096

typedef __hip_bfloat16 bf16;
typedef short bf16x8 __attribute__((ext_vector_type(8)));
typedef float f32x4 __attribute__((ext_vector_type(4)));

static __device__ __forceinline__ void gload_lds16(const bf16* g, bf16* l) {
  __builtin_amdgcn_global_load_lds(
      (const __attribute__((address_space(1))) unsigned int*)(g),
      (__attribute__((address_space(3))) unsigned int*)(l), 16, 0, 0);
}

// ---------------- conversion kernels ----------------

__global__ void cvt_x_kernel(const float* __restrict__ in, bf16* __restrict__ outb) {
  int i = blockIdx.x * 256 + threadIdx.x;   // one float4 per thread
  float4 v = ((const float4*)in)[i];
  union { bf16 h[4]; short4 s4; } u;
  u.h[0] = __float2bfloat16(v.x);
  u.h[1] = __float2bfloat16(v.y);
  u.h[2] = __float2bfloat16(v.z);
  u.h[3] = __float2bfloat16(v.w);
  ((short4*)outb)[i] = u.s4;
}

// batched transpose+convert: in = batch x [R][C] f32 -> out = batch x [C][R] bf16
__global__ void tconv_kernel(const float* __restrict__ in, bf16* __restrict__ outb,
                             int R, int C) {
  int b = blockIdx.y;
  int tiles_c = C >> 6;
  int tr = blockIdx.x / tiles_c;
  int tc = blockIdx.x - tr * tiles_c;
  __shared__ float t[64][65];
  const float* src = in + (size_t)b * R * C;
  bf16* dst = outb + (size_t)b * R * C;
  int r0 = tr << 6, c0 = tc << 6;
#pragma unroll
  for (int i = threadIdx.x; i < 4096; i += 256) {
    int r = i >> 6, c = i & 63;
    t[r][c] = src[(size_t)(r0 + r) * C + c0 + c];
  }
  __syncthreads();
#pragma unroll
  for (int i = threadIdx.x; i < 4096; i += 256) {
    int c = i >> 6, r = i & 63;
    dst[(size_t)(c0 + c) * R + r0 + r] = __float2bfloat16(t[r][c]);
  }
}

// ---------------- GEMM: C[M][N] = A[M][K] * Bt[N][K]^T ----------------
// EPI 0: QKV epilogue (bias + scatter to Qb/Kb/Vt bf16)
// EPI 1: out epilogue (bias + fp32 store)
template <int EPI>
__global__ __launch_bounds__(256) void gemm_kernel(
    const bf16* __restrict__ A, const bf16* __restrict__ Bt,
    int M, int N, int K, int ntn,
    const float* __restrict__ bq, const float* __restrict__ bk,
    const float* __restrict__ bv,
    bf16* __restrict__ Qb, bf16* __restrict__ Kb, bf16* __restrict__ Vt,
    const float* __restrict__ bo, float* __restrict__ outp) {
  __shared__ bf16 sA[2][128 * 32];
  __shared__ bf16 sB[2][128 * 32];
  __shared__ bf16 strans[4][16][20];

  int bid = blockIdx.x;
  int bm = bid / ntn, bn = bid - bm * ntn;
  int tid = threadIdx.x;
  int w = tid >> 6, l = tid & 63;
  int wr = w >> 1, wc = w & 1;
  int l15 = l & 15, g = l >> 4;

  const bf16* Ab = A + (size_t)bm * 128 * K;
  const bf16* Bb = Bt + (size_t)bn * 128 * K;

  int sr = tid >> 2;              // staging row 0..63
  int sc = (tid & 3) << 3;        // staging col (elems)

  f32x4 acc[4][4] = {};
  int NT = K >> 5;
  int cur = 0;

  auto stage = [&](int buf, int kt) {
    const bf16* ga = Ab + (size_t)sr * K + kt * 32 + sc;
    const bf16* gb = Bb + (size_t)sr * K + kt * 32 + sc;
    bf16* la = &sA[buf][w << 9];
    bf16* lb = &sB[buf][w << 9];
    gload_lds16(ga, la);
    gload_lds16(ga + (size_t)64 * K, la + 2048);
    gload_lds16(gb, lb);
    gload_lds16(gb + (size_t)64 * K, lb + 2048);
  };

  stage(0, 0);
  for (int kt = 0; kt < NT; ++kt) {
    __syncthreads();
    if (kt + 1 < NT) stage(cur ^ 1, kt + 1);
    const bf16* pa = &sA[cur][0];
    const bf16* pb = &sB[cur][0];
    bf16x8 af[4], bfr[4];
#pragma unroll
    for (int m = 0; m < 4; ++m)
      af[m] = *(const bf16x8*)&pa[(wr * 64 + m * 16 + l15) * 32 + g * 8];
#pragma unroll
    for (int n = 0; n < 4; ++n)
      bfr[n] = *(const bf16x8*)&pb[(wc * 64 + n * 16 + l15) * 32 + g * 8];
#pragma unroll
    for (int m = 0; m < 4; ++m)
#pragma unroll
      for (int n = 0; n < 4; ++n)
        acc[m][n] = __builtin_amdgcn_mfma_f32_16x16x32_bf16(af[m], bfr[n], acc[m][n], 0, 0, 0);
    cur ^= 1;
  }

  if (EPI == 0) {
#pragma unroll
    for (int n = 0; n < 4; ++n) {
      int j = bn * 128 + wc * 64 + n * 16 + l15;
      int mat = j / 768;
      int jj = j - mat * 768;
      int h = jj >> 6, e = jj & 63;
      const float* bias = (mat == 0) ? bq : (mat == 1) ? bk : bv;
      float bb = bias[h * 64 + e];
#pragma unroll
      for (int m = 0; m < 4; ++m) {
        int s0m = bm * 128 + wr * 64 + m * 16;
        if (mat < 2) {
          bf16* dst = (mat == 0 ? Qb : Kb) + (size_t)h * SEQ * 64;
#pragma unroll
          for (int r = 0; r < 4; ++r)
            dst[(size_t)(s0m + g * 4 + r) * 64 + e] = __float2bfloat16(acc[m][n][r] + bb);
        } else {
          // V: transpose within wave via LDS, store Vt[h][e][s]
#pragma unroll
          for (int r = 0; r < 4; ++r)
            strans[w][g * 4 + r][l15] = __float2bfloat16(acc[m][n][r] + bb);
          int e0f = e - l15;
          bf16* dst = Vt + (size_t)h * SEQ * 64;
#pragma unroll
          for (int r = 0; r < 4; ++r) {
            bf16 val = strans[w][l15][g * 4 + r];
            dst[(size_t)(e0f + g * 4 + r) * SEQ + s0m + l15] = val;
          }
        }
      }
    }
  } else {
#pragma unroll
    for (int n = 0; n < 4; ++n) {
      int j = bn * 128 + wc * 64 + n * 16 + l15;
      float bb = bo[j];
#pragma unroll
      for (int m = 0; m < 4; ++m) {
        int s0m = bm * 128 + wr * 64 + m * 16;
#pragma unroll
        for (int r = 0; r < 4; ++r)
          outp[(size_t)(s0m + g * 4 + r) * HIDDEN + j] = acc[m][n][r] + bb;
      }
    }
  }
}

// ---------------- flash attention ----------------
// grid (SEQ/64, HEADS), 256 threads. wave w handles 16 q rows.
__global__ __launch_bounds__(256) void flash_kernel(
    const bf16* __restrict__ Qb, const bf16* __restrict__ Kb,
    const bf16* __restrict__ Vt, bf16* __restrict__ ctx) {
  __shared__ bf16 pl[4][16][136];
  int h = blockIdx.y;
  int w = threadIdx.x >> 6, l = threadIdx.x & 63;
  int l15 = l & 15, g = l >> 4;
  int q0 = blockIdx.x * 64 + w * 16;

  const bf16* Qh = Qb + (size_t)h * SEQ * 64;
  const bf16* Kh = Kb + (size_t)h * SEQ * 64;
  const bf16* Vh = Vt + (size_t)h * SEQ * 64;  // [64][SEQ]

  bf16x8 aq[2];
  aq[0] = *(const bf16x8*)&Qh[(size_t)(q0 + l15) * 64 + g * 8];
  aq[1] = *(const bf16x8*)&Qh[(size_t)(q0 + l15) * 64 + 32 + g * 8];

  float mrun[4], lrun[4];
  f32x4 cacc[4] = {};
#pragma unroll
  for (int r = 0; r < 4; ++r) { mrun[r] = -INFINITY; lrun[r] = 0.f; }

  for (int t0 = 0; t0 < SEQ; t0 += 128) {
    f32x4 sc8[8] = {};
#pragma unroll
    for (int n = 0; n < 8; ++n) {
      const bf16* kp = &Kh[(size_t)(t0 + n * 16 + l15) * 64 + g * 8];
      bf16x8 b0 = *(const bf16x8*)kp;
      bf16x8 b1 = *(const bf16x8*)(kp + 32);
      sc8[n] = __builtin_amdgcn_mfma_f32_16x16x32_bf16(aq[0], b0, sc8[n], 0, 0, 0);
      sc8[n] = __builtin_amdgcn_mfma_f32_16x16x32_bf16(aq[1], b1, sc8[n], 0, 0, 0);
    }
    float mnew[4], alpha[4], rs[4];
#pragma unroll
    for (int r = 0; r < 4; ++r) {
      float mx = sc8[0][r];
#pragma unroll
      for (int n = 1; n < 8; ++n) mx = fmaxf(mx, sc8[n][r]);
      mx = fmaxf(mx, __shfl_xor(mx, 1));
      mx = fmaxf(mx, __shfl_xor(mx, 2));
      mx = fmaxf(mx, __shfl_xor(mx, 4));
      mx = fmaxf(mx, __shfl_xor(mx, 8));
      float mn = fmaxf(mrun[r], 0.125f * mx);
      alpha[r] = __expf(mrun[r] - mn);
      mnew[r] = mn;
      rs[r] = 0.f;
    }
#pragma unroll
    for (int n = 0; n < 8; ++n) {
#pragma unroll
      for (int r = 0; r < 4; ++r) {
        float p = __expf(0.125f * sc8[n][r] - mnew[r]);
        rs[r] += p;
        pl[w][g * 4 + r][n * 16 + l15] = __float2bfloat16(p);
      }
    }
#pragma unroll
    for (int r = 0; r < 4; ++r) {
      float s = rs[r];
      s += __shfl_xor(s, 1);
      s += __shfl_xor(s, 2);
      s += __shfl_xor(s, 4);
      s += __shfl_xor(s, 8);
      lrun[r] = lrun[r] * alpha[r] + s;
      mrun[r] = mnew[r];
    }
#pragma unroll
    for (int f = 0; f < 4; ++f) {
#pragma unroll
      for (int r = 0; r < 4; ++r) cacc[f][r] *= alpha[r];
    }
#pragma unroll
    for (int kk = 0; kk < 4; ++kk) {
      bf16x8 ap = *(const bf16x8*)&pl[w][l15][kk * 32 + g * 8];
#pragma unroll
      for (int f = 0; f < 4; ++f) {
        bf16x8 bv8 = *(const bf16x8*)&Vh[(size_t)(f * 16 + l15) * SEQ + t0 + kk * 32 + g * 8];
        cacc[f] = __builtin_amdgcn_mfma_f32_16x16x32_bf16(ap, bv8, cacc[f], 0, 0, 0);
      }
    }
  }
  // ctx layout [s][h*64+e] bf16
#pragma unroll
  for (int f = 0; f < 4; ++f) {
#pragma unroll
    for (int r = 0; r < 4; ++r) {
      float v = cacc[f][r] / lrun[r];
      ctx[(size_t)(q0 + g * 4 + r) * HIDDEN + h * 64 + f * 16 + l15] = __float2bfloat16(v);
    }
  }
}

// ---------------- launcher ----------------
extern "C" void kernel_launch(void* const* d_in, const int* in_sizes, int n_in,
                              void* d_out, int out_size, void* d_ws, size_t ws_size,
                              hipStream_t stream) {
  const float* x = (const float*)d_in[0];
  const float* Wq = (const float*)d_in[1];
  const float* Wk = (const float*)d_in[2];
  const float* Wv = (const float*)d_in[3];
  const float* bq = (const float*)d_in[4];
  const float* bk = (const float*)d_in[5];
  const float* bv = (const float*)d_in[6];
  const float* Wo = (const float*)d_in[7];
  const float* bo = (const float*)d_in[8];
  float* outp = (float*)d_out;

  char* ws = (char*)d_ws;
  bf16* xb = (bf16*)ws;   ws += (size_t)SEQ * HIDDEN * 2;
  bf16* Wt = (bf16*)ws;   ws += (size_t)3 * HIDDEN * HIDDEN * 2;
  bf16* Wot = (bf16*)ws;  ws += (size_t)HIDDEN * HIDDEN * 2;
  bf16* Qb = (bf16*)ws;   ws += (size_t)SEQ * HIDDEN * 2;
  bf16* Kb = (bf16*)ws;   ws += (size_t)SEQ * HIDDEN * 2;
  bf16* Vt = (bf16*)ws;   ws += (size_t)SEQ * HIDDEN * 2;
  bf16* ctx = (bf16*)ws;  ws += (size_t)SEQ * HIDDEN * 2;

  cvt_x_kernel<<<SEQ * HIDDEN / 4 / 256, 256, 0, stream>>>(x, xb);
  tconv_kernel<<<dim3(12, 12), 256, 0, stream>>>(Wq, Wt, 768, 64);
  tconv_kernel<<<dim3(12, 12), 256, 0, stream>>>(Wk, Wt + 589824, 768, 64);
  tconv_kernel<<<dim3(12, 12), 256, 0, stream>>>(Wv, Wt + 2 * 589824, 768, 64);
  tconv_kernel<<<dim3(144, 1), 256, 0, stream>>>(Wo, Wot, 768, 768);

  gemm_kernel<0><<<32 * 18, 256, 0, stream>>>(xb, Wt, SEQ, 2304, 768, 18,
                                              bq, bk, bv, Qb, Kb, Vt, nullptr, nullptr);

  flash_kernel<<<dim3(64, 12), 256, 0, stream>>>(Qb, Kb, Vt, ctx);

  gemm_kernel<1><<<32 * 6, 256, 0, stream>>>(ctx, Wot, SEQ, 768, 768, 6,
                                             nullptr, nullptr, nullptr, nullptr, nullptr,
                                             nullptr, bo, outp);
}

// Round 2
// 270.255 us; speedup vs baseline: 1.5900x; 1.5900x over previous
//
#include <hip/hip_runtime.h>
#include <hip/hip_bf16.h>
#include <cstdint>
#include <cstddef>

#define HIDDEN 768
#define HEADS 12
#define HD 64
#define SEQ 4096

typedef __hip_bfloat16 bf16;
typedef short bf16x8 __attribute__((ext_vector_type(8)));
typedef float f32x4 __attribute__((ext_vector_type(4)));

static __device__ __forceinline__ void gload_lds16(const bf16* g, bf16* l) {
  __builtin_amdgcn_global_load_lds(
      (const __attribute__((address_space(1))) unsigned int*)(g),
      (__attribute__((address_space(3))) unsigned int*)(l), 16, 0, 0);
}

// ---------------- conversion kernels ----------------

__global__ void cvt_x_kernel(const float* __restrict__ in, bf16* __restrict__ outb) {
  int i = blockIdx.x * 256 + threadIdx.x;   // one float4 per thread
  float4 v = ((const float4*)in)[i];
  union { bf16 h[4]; short4 s4; } u;
  u.h[0] = __float2bfloat16(v.x);
  u.h[1] = __float2bfloat16(v.y);
  u.h[2] = __float2bfloat16(v.z);
  u.h[3] = __float2bfloat16(v.w);
  ((short4*)outb)[i] = u.s4;
}

// batched transpose+convert: in = batch x [R][C] f32 -> out = batch x [C][R] bf16
__global__ void tconv_kernel(const float* __restrict__ in, bf16* __restrict__ outb,
                             int R, int C) {
  int b = blockIdx.y;
  int tiles_c = C >> 6;
  int tr = blockIdx.x / tiles_c;
  int tc = blockIdx.x - tr * tiles_c;
  __shared__ float t[64][65];
  const float* src = in + (size_t)b * R * C;
  bf16* dst = outb + (size_t)b * R * C;
  int r0 = tr << 6, c0 = tc << 6;
#pragma unroll
  for (int i = threadIdx.x; i < 4096; i += 256) {
    int r = i >> 6, c = i & 63;
    t[r][c] = src[(size_t)(r0 + r) * C + c0 + c];
  }
  __syncthreads();
#pragma unroll
  for (int i = threadIdx.x; i < 4096; i += 256) {
    int c = i >> 6, r = i & 63;
    dst[(size_t)(c0 + c) * R + r0 + r] = __float2bfloat16(t[r][c]);
  }
}

// ---------------- GEMM: C[M][N] = A[M][K] * Bt[N][K]^T ----------------
template <int EPI>
__global__ __launch_bounds__(256) void gemm_kernel(
    const bf16* __restrict__ A, const bf16* __restrict__ Bt,
    int M, int N, int K, int ntn,
    const float* __restrict__ bq, const float* __restrict__ bk,
    const float* __restrict__ bv,
    bf16* __restrict__ Qb, bf16* __restrict__ Kb, bf16* __restrict__ Vt,
    const float* __restrict__ bo, float* __restrict__ outp) {
  __shared__ bf16 sA[2][128 * 32];
  __shared__ bf16 sB[2][128 * 32];
  __shared__ bf16 strans[4][16][20];

  int bid = blockIdx.x;
  int bm = bid / ntn, bn = bid - bm * ntn;
  int tid = threadIdx.x;
  int w = tid >> 6, l = tid & 63;
  int wr = w >> 1, wc = w & 1;
  int l15 = l & 15, g = l >> 4;

  const bf16* Ab = A + (size_t)bm * 128 * K;
  const bf16* Bb = Bt + (size_t)bn * 128 * K;

  int sr = tid >> 2;              // staging row 0..63
  int sc = (tid & 3) << 3;        // staging col (elems)

  f32x4 acc[4][4] = {};
  int NT = K >> 5;
  int cur = 0;

  auto stage = [&](int buf, int kt) {
    const bf16* ga = Ab + (size_t)sr * K + kt * 32 + sc;
    const bf16* gb = Bb + (size_t)sr * K + kt * 32 + sc;
    bf16* la = &sA[buf][w << 9];
    bf16* lb = &sB[buf][w << 9];
    gload_lds16(ga, la);
    gload_lds16(ga + (size_t)64 * K, la + 2048);
    gload_lds16(gb, lb);
    gload_lds16(gb + (size_t)64 * K, lb + 2048);
  };

  stage(0, 0);
  for (int kt = 0; kt < NT; ++kt) {
    __syncthreads();
    if (kt + 1 < NT) stage(cur ^ 1, kt + 1);
    const bf16* pa = &sA[cur][0];
    const bf16* pb = &sB[cur][0];
    bf16x8 af[4], bfr[4];
#pragma unroll
    for (int m = 0; m < 4; ++m)
      af[m] = *(const bf16x8*)&pa[(wr * 64 + m * 16 + l15) * 32 + g * 8];
#pragma unroll
    for (int n = 0; n < 4; ++n)
      bfr[n] = *(const bf16x8*)&pb[(wc * 64 + n * 16 + l15) * 32 + g * 8];
#pragma unroll
    for (int m = 0; m < 4; ++m)
#pragma unroll
      for (int n = 0; n < 4; ++n)
        acc[m][n] = __builtin_amdgcn_mfma_f32_16x16x32_bf16(af[m], bfr[n], acc[m][n], 0, 0, 0);
    cur ^= 1;
  }

  if (EPI == 0) {
#pragma unroll
    for (int n = 0; n < 4; ++n) {
      int j = bn * 128 + wc * 64 + n * 16 + l15;
      int mat = j / 768;
      int jj = j - mat * 768;
      int h = jj >> 6, e = jj & 63;
      const float* bias = (mat == 0) ? bq : (mat == 1) ? bk : bv;
      float bb = bias[h * 64 + e];
#pragma unroll
      for (int m = 0; m < 4; ++m) {
        int s0m = bm * 128 + wr * 64 + m * 16;
        if (mat < 2) {
          bf16* dst = (mat == 0 ? Qb : Kb) + (size_t)h * SEQ * 64;
#pragma unroll
          for (int r = 0; r < 4; ++r)
            dst[(size_t)(s0m + g * 4 + r) * 64 + e] = __float2bfloat16(acc[m][n][r] + bb);
        } else {
#pragma unroll
          for (int r = 0; r < 4; ++r)
            strans[w][g * 4 + r][l15] = __float2bfloat16(acc[m][n][r] + bb);
          int e0f = e - l15;
          bf16* dst = Vt + (size_t)h * SEQ * 64;
#pragma unroll
          for (int r = 0; r < 4; ++r) {
            bf16 val = strans[w][l15][g * 4 + r];
            dst[(size_t)(e0f + g * 4 + r) * SEQ + s0m + l15] = val;
          }
        }
      }
    }
  } else {
#pragma unroll
    for (int n = 0; n < 4; ++n) {
      int j = bn * 128 + wc * 64 + n * 16 + l15;
      float bb = bo[j];
#pragma unroll
      for (int m = 0; m < 4; ++m) {
        int s0m = bm * 128 + wr * 64 + m * 16;
#pragma unroll
        for (int r = 0; r < 4; ++r)
          outp[(size_t)(s0m + g * 4 + r) * HIDDEN + j] = acc[m][n][r] + bb;
      }
    }
  }
}

// ---------------- flash attention v2 ----------------
// grid (SEQ/128, HEADS), 256 threads (4 waves x 32 q-rows).
// K/V tiles (KVBLK=64) staged in LDS via global_load_lds, double-buffered,
// XOR-swizzled (chunk ^= row&7) via pre-swizzled global source (rule #21).
__global__ __launch_bounds__(256) void flash_kernel(
    const bf16* __restrict__ Qb, const bf16* __restrict__ Kb,
    const bf16* __restrict__ Vt, bf16* __restrict__ ctx) {
  __shared__ bf16 sK[2][64 * 64];   // [t][e], 128B rows, swizzled
  __shared__ bf16 sV[2][64 * 64];   // [e][t], 128B rows, swizzled
  __shared__ bf16 sP[4][32 * 64];   // per-wave P [q][t], swizzled

  const int head = blockIdx.y;
  const int w = threadIdx.x >> 6, l = threadIdx.x & 63;
  const int l15 = l & 15, g = l >> 4;
  const int sw = l15 & 7;
  const int q0w = blockIdx.x * 128 + w * 32;

  const bf16* Qh = Qb + (size_t)head * SEQ * 64;
  const bf16* Kh = Kb + (size_t)head * SEQ * 64;
  const bf16* Vh = Vt + (size_t)head * SEQ * 64;   // [64][SEQ]

  bf16x8 aq[2][2];
#pragma unroll
  for (int m = 0; m < 2; ++m)
#pragma unroll
    for (int hf = 0; hf < 2; ++hf)
      aq[m][hf] = *(const bf16x8*)&Qh[(size_t)(q0w + m * 16 + l15) * 64 + hf * 32 + g * 8];

  float mrun[2][4], lsum[2][4];
  f32x4 cacc[4][2] = {};
#pragma unroll
  for (int m = 0; m < 2; ++m)
#pragma unroll
    for (int r = 0; r < 4; ++r) { mrun[m][r] = -1e30f; lsum[m][r] = 0.f; }

  const int lr8 = l >> 3;            // row-in-call 0..7
  const int csrc = (l & 7) ^ lr8;    // pre-swizzled source chunk

  auto stage = [&](int buf, int kt) {
    int t0 = kt * 64;
    // K rows w*16..w*16+15 (t-dim), 2 calls x 8 rows of 128B
    const bf16* gk = Kh + (size_t)(t0 + w * 16 + lr8) * 64 + csrc * 8;
    bf16* lk = &sK[buf][(w * 16) * 64];
    gload_lds16(gk, lk);
    gload_lds16(gk + (size_t)8 * 64, lk + 8 * 64);
    // V rows w*16..w*16+15 (e-dim), stride SEQ
    const bf16* gv = Vh + (size_t)(w * 16 + lr8) * SEQ + t0 + csrc * 8;
    bf16* lv = &sV[buf][(w * 16) * 64];
    gload_lds16(gv, lv);
    gload_lds16(gv + (size_t)8 * SEQ, lv + 8 * 64);
  };

  stage(0, 0);
  int cur = 0;
  bf16* sPw = &sP[w][0];

  for (int kt = 0; kt < SEQ / 64; ++kt) {
    __syncthreads();               // drains prev stage (vmcnt) + protects buffers
    if (kt + 1 < SEQ / 64) stage(cur ^ 1, kt + 1);
    const bf16* kb = &sK[cur][0];
    const bf16* vb = &sV[cur][0];

    // ---- QK^T ----
    f32x4 sc8[4][2] = {};
#pragma unroll
    for (int n = 0; n < 4; ++n) {
      bf16x8 b0 = *(const bf16x8*)&kb[(n * 16 + l15) * 64 + (g ^ sw) * 8];
      bf16x8 b1 = *(const bf16x8*)&kb[(n * 16 + l15) * 64 + ((4 + g) ^ sw) * 8];
#pragma unroll
      for (int m = 0; m < 2; ++m) {
        sc8[n][m] = __builtin_amdgcn_mfma_f32_16x16x32_bf16(aq[m][0], b0, sc8[n][m], 0, 0, 0);
        sc8[n][m] = __builtin_amdgcn_mfma_f32_16x16x32_bf16(aq[m][1], b1, sc8[n][m], 0, 0, 0);
      }
    }

    // ---- online softmax (scaled domain, deferred l-sum reduce) ----
    float alpha[2][4];
#pragma unroll
    for (int m = 0; m < 2; ++m)
#pragma unroll
      for (int r = 0; r < 4; ++r) {
        float mx = fmaxf(fmaxf(sc8[0][m][r], sc8[1][m][r]),
                         fmaxf(sc8[2][m][r], sc8[3][m][r]));
        mx = fmaxf(mx, __shfl_xor(mx, 1));
        mx = fmaxf(mx, __shfl_xor(mx, 2));
        mx = fmaxf(mx, __shfl_xor(mx, 4));
        mx = fmaxf(mx, __shfl_xor(mx, 8));
        float mn = fmaxf(mrun[m][r], 0.125f * mx);
        alpha[m][r] = __expf(mrun[m][r] - mn);
        mrun[m][r] = mn;
        lsum[m][r] *= alpha[m][r];
      }
#pragma unroll
    for (int f = 0; f < 4; ++f)
#pragma unroll
      for (int m = 0; m < 2; ++m)
#pragma unroll
        for (int r = 0; r < 4; ++r) cacc[f][m][r] *= alpha[m][r];

    // ---- P = exp(S - m), write swizzled to per-wave sP ----
#pragma unroll
    for (int n = 0; n < 4; ++n)
#pragma unroll
      for (int m = 0; m < 2; ++m)
#pragma unroll
        for (int r = 0; r < 4; ++r) {
          float p = __expf(fmaf(0.125f, sc8[n][m][r], -mrun[m][r]));
          lsum[m][r] += p;
          int q = m * 16 + g * 4 + r;
          int cst = (n * 2 + (l15 >> 3)) ^ (q & 7);
          sPw[q * 64 + cst * 8 + (l15 & 7)] = __float2bfloat16(p);
        }

    // ---- PV ----
#pragma unroll
    for (int kkl = 0; kkl < 2; ++kkl) {
      bf16x8 ap[2];
#pragma unroll
      for (int m = 0; m < 2; ++m)
        ap[m] = *(const bf16x8*)&sPw[(m * 16 + l15) * 64 + ((kkl * 4 + g) ^ sw) * 8];
#pragma unroll
      for (int f = 0; f < 4; ++f) {
        bf16x8 bv8 = *(const bf16x8*)&vb[(f * 16 + l15) * 64 + ((kkl * 4 + g) ^ sw) * 8];
#pragma unroll
        for (int m = 0; m < 2; ++m)
          cacc[f][m] = __builtin_amdgcn_mfma_f32_16x16x32_bf16(ap[m], bv8, cacc[f][m], 0, 0, 0);
      }
    }
    cur ^= 1;
  }

  // ---- epilogue: final l reduce + normalize + store ----
#pragma unroll
  for (int m = 0; m < 2; ++m)
#pragma unroll
    for (int r = 0; r < 4; ++r) {
      float s = lsum[m][r];
      s += __shfl_xor(s, 1);
      s += __shfl_xor(s, 2);
      s += __shfl_xor(s, 4);
      s += __shfl_xor(s, 8);
      float inv = 1.0f / s;
#pragma unroll
      for (int f = 0; f < 4; ++f)
        ctx[(size_t)(q0w + m * 16 + g * 4 + r) * HIDDEN + head * 64 + f * 16 + l15] =
            __float2bfloat16(cacc[f][m][r] * inv);
    }
}

// ---------------- launcher ----------------
extern "C" void kernel_launch(void* const* d_in, const int* in_sizes, int n_in,
                              void* d_out, int out_size, void* d_ws, size_t ws_size,
                              hipStream_t stream) {
  const float* x = (const float*)d_in[0];
  const float* Wq = (const float*)d_in[1];
  const float* Wk = (const float*)d_in[2];
  const float* Wv = (const float*)d_in[3];
  const float* bq = (const float*)d_in[4];
  const float* bk = (const float*)d_in[5];
  const float* bv = (const float*)d_in[6];
  const float* Wo = (const float*)d_in[7];
  const float* bo = (const float*)d_in[8];
  float* outp = (float*)d_out;

  char* ws = (char*)d_ws;
  bf16* xb = (bf16*)ws;   ws += (size_t)SEQ * HIDDEN * 2;
  bf16* Wt = (bf16*)ws;   ws += (size_t)3 * HIDDEN * HIDDEN * 2;
  bf16* Wot = (bf16*)ws;  ws += (size_t)HIDDEN * HIDDEN * 2;
  bf16* Qb = (bf16*)ws;   ws += (size_t)SEQ * HIDDEN * 2;
  bf16* Kb = (bf16*)ws;   ws += (size_t)SEQ * HIDDEN * 2;
  bf16* Vt = (bf16*)ws;   ws += (size_t)SEQ * HIDDEN * 2;
  bf16* ctx = (bf16*)ws;  ws += (size_t)SEQ * HIDDEN * 2;

  cvt_x_kernel<<<SEQ * HIDDEN / 4 / 256, 256, 0, stream>>>(x, xb);
  tconv_kernel<<<dim3(12, 12), 256, 0, stream>>>(Wq, Wt, 768, 64);
  tconv_kernel<<<dim3(12, 12), 256, 0, stream>>>(Wk, Wt + 589824, 768, 64);
  tconv_kernel<<<dim3(12, 12), 256, 0, stream>>>(Wv, Wt + 2 * 589824, 768, 64);
  tconv_kernel<<<dim3(144, 1), 256, 0, stream>>>(Wo, Wot, 768, 768);

  gemm_kernel<0><<<32 * 18, 256, 0, stream>>>(xb, Wt, SEQ, 2304, 768, 18,
                                              bq, bk, bv, Qb, Kb, Vt, nullptr, nullptr);

  flash_kernel<<<dim3(32, 12), 256, 0, stream>>>(Qb, Kb, Vt, ctx);

  gemm_kernel<1><<<32 * 6, 256, 0, stream>>>(ctx, Wot, SEQ, 768, 768, 6,
                                             nullptr, nullptr, nullptr, nullptr, nullptr,
                                             nullptr, bo, outp);
}

// Round 4
// 210.666 us; speedup vs baseline: 2.0397x; 1.2829x over previous
//
#include <hip/hip_runtime.h>
#include <hip/hip_bf16.h>
#include <cstdint>
#include <cstddef>

#define HIDDEN 768
#define HEADS 12
#define HD 64
#define SEQ 4096

typedef __hip_bfloat16 bf16;
typedef short bf16x8 __attribute__((ext_vector_type(8)));
typedef float f32x4 __attribute__((ext_vector_type(4)));

// 0.125 (1/sqrt(64)) * log2(e): folded into Q so softmax runs in exp2 domain
#define QSCALE 0.18033688011112042f

static __device__ __forceinline__ void gload_lds16(const bf16* g, bf16* l) {
  __builtin_amdgcn_global_load_lds(
      (const __attribute__((address_space(1))) unsigned int*)(g),
      (__attribute__((address_space(3))) unsigned int*)(l), 16, 0, 0);
}

// ---------------- conversion kernels ----------------

__global__ void cvt_x_kernel(const float* __restrict__ in, bf16* __restrict__ outb) {
  int i = blockIdx.x * 256 + threadIdx.x;   // one float4 per thread
  float4 v = ((const float4*)in)[i];
  union { bf16 h[4]; short4 s4; } u;
  u.h[0] = __float2bfloat16(v.x);
  u.h[1] = __float2bfloat16(v.y);
  u.h[2] = __float2bfloat16(v.z);
  u.h[3] = __float2bfloat16(v.w);
  ((short4*)outb)[i] = u.s4;
}

// batched transpose+convert: in = batch x [R][C] f32 -> out = batch x [C][R] bf16
__global__ void tconv_kernel(const float* __restrict__ in, bf16* __restrict__ outb,
                             int R, int C) {
  int b = blockIdx.y;
  int tiles_c = C >> 6;
  int tr = blockIdx.x / tiles_c;
  int tc = blockIdx.x - tr * tiles_c;
  __shared__ float t[64][65];
  const float* src = in + (size_t)b * R * C;
  bf16* dst = outb + (size_t)b * R * C;
  int r0 = tr << 6, c0 = tc << 6;
#pragma unroll
  for (int i = threadIdx.x; i < 4096; i += 256) {
    int r = i >> 6, c = i & 63;
    t[r][c] = src[(size_t)(r0 + r) * C + c0 + c];
  }
  __syncthreads();
#pragma unroll
  for (int i = threadIdx.x; i < 4096; i += 256) {
    int c = i >> 6, r = i & 63;
    dst[(size_t)(c0 + c) * R + r0 + r] = __float2bfloat16(t[r][c]);
  }
}

// ---------------- GEMM: C[M][N] = A[M][K] * Bt[N][K]^T ----------------
template <int EPI>
__global__ __launch_bounds__(256) void gemm_kernel(
    const bf16* __restrict__ A, const bf16* __restrict__ Bt,
    int M, int N, int K, int ntn,
    const float* __restrict__ bq, const float* __restrict__ bk,
    const float* __restrict__ bv,
    bf16* __restrict__ Qb, bf16* __restrict__ Kb, bf16* __restrict__ Vt,
    const float* __restrict__ bo, float* __restrict__ outp) {
  __shared__ bf16 sA[2][128 * 32];
  __shared__ bf16 sB[2][128 * 32];
  __shared__ bf16 strans[4][16][20];

  int bid = blockIdx.x;
  int bm = bid / ntn, bn = bid - bm * ntn;
  int tid = threadIdx.x;
  int w = tid >> 6, l = tid & 63;
  int wr = w >> 1, wc = w & 1;
  int l15 = l & 15, g = l >> 4;

  const bf16* Ab = A + (size_t)bm * 128 * K;
  const bf16* Bb = Bt + (size_t)bn * 128 * K;

  int sr = tid >> 2;              // staging row 0..63
  int sc = (tid & 3) << 3;        // staging col (elems)

  f32x4 acc[4][4] = {};
  int NT = K >> 5;
  int cur = 0;

  auto stage = [&](int buf, int kt) {
    const bf16* ga = Ab + (size_t)sr * K + kt * 32 + sc;
    const bf16* gb = Bb + (size_t)sr * K + kt * 32 + sc;
    bf16* la = &sA[buf][w << 9];
    bf16* lb = &sB[buf][w << 9];
    gload_lds16(ga, la);
    gload_lds16(ga + (size_t)64 * K, la + 2048);
    gload_lds16(gb, lb);
    gload_lds16(gb + (size_t)64 * K, lb + 2048);
  };

  stage(0, 0);
  for (int kt = 0; kt < NT; ++kt) {
    __syncthreads();
    if (kt + 1 < NT) stage(cur ^ 1, kt + 1);
    const bf16* pa = &sA[cur][0];
    const bf16* pb = &sB[cur][0];
    bf16x8 af[4], bfr[4];
#pragma unroll
    for (int m = 0; m < 4; ++m)
      af[m] = *(const bf16x8*)&pa[(wr * 64 + m * 16 + l15) * 32 + g * 8];
#pragma unroll
    for (int n = 0; n < 4; ++n)
      bfr[n] = *(const bf16x8*)&pb[(wc * 64 + n * 16 + l15) * 32 + g * 8];
#pragma unroll
    for (int m = 0; m < 4; ++m)
#pragma unroll
      for (int n = 0; n < 4; ++n)
        acc[m][n] = __builtin_amdgcn_mfma_f32_16x16x32_bf16(af[m], bfr[n], acc[m][n], 0, 0, 0);
    cur ^= 1;
  }

  if (EPI == 0) {
#pragma unroll
    for (int n = 0; n < 4; ++n) {
      int j = bn * 128 + wc * 64 + n * 16 + l15;
      int mat = j / 768;
      int jj = j - mat * 768;
      int h = jj >> 6, e = jj & 63;
      const float* bias = (mat == 0) ? bq : (mat == 1) ? bk : bv;
      float bb = bias[h * 64 + e];
      float scl = (mat == 0) ? QSCALE : 1.0f;   // Q pre-scaled into exp2 domain
#pragma unroll
      for (int m = 0; m < 4; ++m) {
        int s0m = bm * 128 + wr * 64 + m * 16;
        if (mat < 2) {
          bf16* dst = (mat == 0 ? Qb : Kb) + (size_t)h * SEQ * 64;
#pragma unroll
          for (int r = 0; r < 4; ++r)
            dst[(size_t)(s0m + g * 4 + r) * 64 + e] = __float2bfloat16((acc[m][n][r] + bb) * scl);
        } else {
#pragma unroll
          for (int r = 0; r < 4; ++r)
            strans[w][g * 4 + r][l15] = __float2bfloat16(acc[m][n][r] + bb);
          int e0f = e - l15;
          bf16* dst = Vt + (size_t)h * SEQ * 64;
#pragma unroll
          for (int r = 0; r < 4; ++r) {
            bf16 val = strans[w][l15][g * 4 + r];
            dst[(size_t)(e0f + g * 4 + r) * SEQ + s0m + l15] = val;
          }
        }
      }
    }
  } else {
#pragma unroll
    for (int n = 0; n < 4; ++n) {
      int j = bn * 128 + wc * 64 + n * 16 + l15;
      float bb = bo[j];
#pragma unroll
      for (int m = 0; m < 4; ++m) {
        int s0m = bm * 128 + wr * 64 + m * 16;
#pragma unroll
        for (int r = 0; r < 4; ++r)
          outp[(size_t)(s0m + g * 4 + r) * HIDDEN + j] = acc[m][n][r] + bb;
      }
    }
  }
}

// ---------------- flash attention v3 ----------------
// grid (SEQ/64, HEADS) = 768 blocks (3/CU exact), 256 threads, 16 q-rows/wave.
// K/V staged in LDS (global_load_lds w16), double-buffered, XOR-swizzled via
// pre-swizzled global source. Softmax in exp2 domain (scale folded into Qb),
// defer-rescale (THR=8), deferred l-sum reduce.
__global__ __launch_bounds__(256) void flash_kernel(
    const bf16* __restrict__ Qb, const bf16* __restrict__ Kb,
    const bf16* __restrict__ Vt, bf16* __restrict__ ctx) {
  __shared__ bf16 sK[2][64 * 64];   // [t][e], 128B rows, swizzled
  __shared__ bf16 sV[2][64 * 64];   // [e][t], 128B rows, swizzled
  __shared__ bf16 sP[4][16 * 64];   // per-wave P [q][t], swizzled

  const int head = blockIdx.y;
  const int w = threadIdx.x >> 6, l = threadIdx.x & 63;
  const int l15 = l & 15, g = l >> 4;
  const int sw = l15 & 7;
  const int q0w = blockIdx.x * 64 + w * 16;

  const bf16* Qh = Qb + (size_t)head * SEQ * 64;
  const bf16* Kh = Kb + (size_t)head * SEQ * 64;
  const bf16* Vh = Vt + (size_t)head * SEQ * 64;   // [64][SEQ]

  bf16x8 aq[2];
  aq[0] = *(const bf16x8*)&Qh[(size_t)(q0w + l15) * 64 + g * 8];
  aq[1] = *(const bf16x8*)&Qh[(size_t)(q0w + l15) * 64 + 32 + g * 8];

  float mrun[4], lsum[4];
  f32x4 cacc[4] = {};
#pragma unroll
  for (int r = 0; r < 4; ++r) { mrun[r] = -1e30f; lsum[r] = 0.f; }

  const int lr8 = l >> 3;            // row-in-call 0..7
  const int csrc = (l & 7) ^ lr8;    // pre-swizzled source chunk

  auto stage = [&](int buf, int kt) {
    int t0 = kt * 64;
    const bf16* gk = Kh + (size_t)(t0 + w * 16 + lr8) * 64 + csrc * 8;
    bf16* lk = &sK[buf][(w * 16) * 64];
    gload_lds16(gk, lk);
    gload_lds16(gk + (size_t)8 * 64, lk + 8 * 64);
    const bf16* gv = Vh + (size_t)(w * 16 + lr8) * SEQ + t0 + csrc * 8;
    bf16* lv = &sV[buf][(w * 16) * 64];
    gload_lds16(gv, lv);
    gload_lds16(gv + (size_t)8 * SEQ, lv + 8 * 64);
  };

  stage(0, 0);
  int cur = 0;
  bf16* sPw = &sP[w][0];

  for (int kt = 0; kt < SEQ / 64; ++kt) {
    __syncthreads();               // drains prev stage (vmcnt) + protects buffers
    if (kt + 1 < SEQ / 64) stage(cur ^ 1, kt + 1);
    const bf16* kb = &sK[cur][0];
    const bf16* vb = &sV[cur][0];

    // ---- QK^T (scores already in exp2 domain) ----
    f32x4 sc8[4] = {};
#pragma unroll
    for (int n = 0; n < 4; ++n) {
      bf16x8 b0 = *(const bf16x8*)&kb[(n * 16 + l15) * 64 + (g ^ sw) * 8];
      bf16x8 b1 = *(const bf16x8*)&kb[(n * 16 + l15) * 64 + ((4 + g) ^ sw) * 8];
      sc8[n] = __builtin_amdgcn_mfma_f32_16x16x32_bf16(aq[0], b0, sc8[n], 0, 0, 0);
      sc8[n] = __builtin_amdgcn_mfma_f32_16x16x32_bf16(aq[1], b1, sc8[n], 0, 0, 0);
    }

    // ---- online softmax: max + defer-rescale (THR=8) ----
    float mx[4];
    bool need = false;
#pragma unroll
    for (int r = 0; r < 4; ++r) {
      float v0 = fmaxf(fmaxf(sc8[0][r], sc8[1][r]), fmaxf(sc8[2][r], sc8[3][r]));
      v0 = fmaxf(v0, __shfl_xor(v0, 1));
      v0 = fmaxf(v0, __shfl_xor(v0, 2));
      v0 = fmaxf(v0, __shfl_xor(v0, 4));
      v0 = fmaxf(v0, __shfl_xor(v0, 8));
      mx[r] = v0;
      need = need || (v0 > mrun[r] + 8.0f);
    }
    if (__any(need)) {
#pragma unroll
      for (int r = 0; r < 4; ++r) {
        float mn = fmaxf(mrun[r], mx[r]);
        float a = __builtin_amdgcn_exp2f(mrun[r] - mn);
        mrun[r] = mn;
        lsum[r] *= a;
#pragma unroll
        for (int f = 0; f < 4; ++f) cacc[f][r] *= a;
      }
    }

    // ---- P = exp2(S - m), write swizzled to per-wave sP ----
#pragma unroll
    for (int n = 0; n < 4; ++n)
#pragma unroll
      for (int r = 0; r < 4; ++r) {
        float p = __builtin_amdgcn_exp2f(sc8[n][r] - mrun[r]);
        lsum[r] += p;
        int q = g * 4 + r;
        int cst = (n * 2 + (l15 >> 3)) ^ (q & 7);
        sPw[q * 64 + cst * 8 + (l15 & 7)] = __float2bfloat16(p);
      }

    // ---- PV ----
#pragma unroll
    for (int kkl = 0; kkl < 2; ++kkl) {
      bf16x8 ap = *(const bf16x8*)&sPw[l15 * 64 + ((kkl * 4 + g) ^ sw) * 8];
#pragma unroll
      for (int f = 0; f < 4; ++f) {
        bf16x8 bv8 = *(const bf16x8*)&vb[(f * 16 + l15) * 64 + ((kkl * 4 + g) ^ sw) * 8];
        cacc[f] = __builtin_amdgcn_mfma_f32_16x16x32_bf16(ap, bv8, cacc[f], 0, 0, 0);
      }
    }
    cur ^= 1;
  }

  // ---- epilogue: final l reduce + normalize + store ----
#pragma unroll
  for (int r = 0; r < 4; ++r) {
    float s = lsum[r];
    s += __shfl_xor(s, 1);
    s += __shfl_xor(s, 2);
    s += __shfl_xor(s, 4);
    s += __shfl_xor(s, 8);
    float inv = 1.0f / s;
#pragma unroll
    for (int f = 0; f < 4; ++f)
      ctx[(size_t)(q0w + g * 4 + r) * HIDDEN + head * 64 + f * 16 + l15] =
          __float2bfloat16(cacc[f][r] * inv);
  }
}

// ---------------- launcher ----------------
extern "C" void kernel_launch(void* const* d_in, const int* in_sizes, int n_in,
                              void* d_out, int out_size, void* d_ws, size_t ws_size,
                              hipStream_t stream) {
  const float* x = (const float*)d_in[0];
  const float* Wq = (const float*)d_in[1];
  const float* Wk = (const float*)d_in[2];
  const float* Wv = (const float*)d_in[3];
  const float* bq = (const float*)d_in[4];
  const float* bk = (const float*)d_in[5];
  const float* bv = (const float*)d_in[6];
  const float* Wo = (const float*)d_in[7];
  const float* bo = (const float*)d_in[8];
  float* outp = (float*)d_out;

  char* ws = (char*)d_ws;
  bf16* xb = (bf16*)ws;   ws += (size_t)SEQ * HIDDEN * 2;
  bf16* Wt = (bf16*)ws;   ws += (size_t)3 * HIDDEN * HIDDEN * 2;
  bf16* Wot = (bf16*)ws;  ws += (size_t)HIDDEN * HIDDEN * 2;
  bf16* Qb = (bf16*)ws;   ws += (size_t)SEQ * HIDDEN * 2;
  bf16* Kb = (bf16*)ws;   ws += (size_t)SEQ * HIDDEN * 2;
  bf16* Vt = (bf16*)ws;   ws += (size_t)SEQ * HIDDEN * 2;
  bf16* ctx = (bf16*)ws;  ws += (size_t)SEQ * HIDDEN * 2;

  cvt_x_kernel<<<SEQ * HIDDEN / 4 / 256, 256, 0, stream>>>(x, xb);
  tconv_kernel<<<dim3(12, 12), 256, 0, stream>>>(Wq, Wt, 768, 64);
  tconv_kernel<<<dim3(12, 12), 256, 0, stream>>>(Wk, Wt + 589824, 768, 64);
  tconv_kernel<<<dim3(12, 12), 256, 0, stream>>>(Wv, Wt + 2 * 589824, 768, 64);
  tconv_kernel<<<dim3(144, 1), 256, 0, stream>>>(Wo, Wot, 768, 768);

  gemm_kernel<0><<<32 * 18, 256, 0, stream>>>(xb, Wt, SEQ, 2304, 768, 18,
                                              bq, bk, bv, Qb, Kb, Vt, nullptr, nullptr);

  flash_kernel<<<dim3(64, 12), 256, 0, stream>>>(Qb, Kb, Vt, ctx);

  gemm_kernel<1><<<32 * 6, 256, 0, stream>>>(ctx, Wot, SEQ, 768, 768, 6,
                                             nullptr, nullptr, nullptr, nullptr, nullptr,
                                             nullptr, bo, outp);
}

// Round 5
// 180.952 us; speedup vs baseline: 2.3746x; 1.1642x over previous
//
#include <hip/hip_runtime.h>
#include <hip/hip_bf16.h>
#include <cstdint>
#include <cstddef>

#define HIDDEN 768
#define HEADS 12
#define HD 64
#define SEQ 4096

typedef __hip_bfloat16 bf16;
typedef short bf16x8 __attribute__((ext_vector_type(8)));
typedef float f32x4 __attribute__((ext_vector_type(4)));

// 0.125 (1/sqrt(64)) * log2(e): folded into Q so softmax runs in exp2 domain
#define QSCALE 0.18033688011112042f

static __device__ __forceinline__ void gload_lds16(const bf16* g, bf16* l) {
  __builtin_amdgcn_global_load_lds(
      (const __attribute__((address_space(1))) unsigned int*)(g),
      (__attribute__((address_space(3))) unsigned int*)(l), 16, 0, 0);
}

static __device__ __forceinline__ unsigned cvt_pk_bf16(float lo, float hi) {
  unsigned r;
  asm("v_cvt_pk_bf16_f32 %0, %1, %2" : "=v"(r) : "v"(lo), "v"(hi));
  return r;
}

// ---------------- conversion kernels ----------------

__global__ void cvt_x_kernel(const float* __restrict__ in, bf16* __restrict__ outb) {
  int i = blockIdx.x * 256 + threadIdx.x;   // one float4 per thread
  float4 v = ((const float4*)in)[i];
  union { bf16 h[4]; short4 s4; } u;
  u.h[0] = __float2bfloat16(v.x);
  u.h[1] = __float2bfloat16(v.y);
  u.h[2] = __float2bfloat16(v.z);
  u.h[3] = __float2bfloat16(v.w);
  ((short4*)outb)[i] = u.s4;
}

// batched transpose+convert: in = batch x [R][C] f32 -> out = batch x [C][R] bf16
__global__ void tconv_kernel(const float* __restrict__ in, bf16* __restrict__ outb,
                             int R, int C) {
  int b = blockIdx.y;
  int tiles_c = C >> 6;
  int tr = blockIdx.x / tiles_c;
  int tc = blockIdx.x - tr * tiles_c;
  __shared__ float t[64][65];
  const float* src = in + (size_t)b * R * C;
  bf16* dst = outb + (size_t)b * R * C;
  int r0 = tr << 6, c0 = tc << 6;
#pragma unroll
  for (int i = threadIdx.x; i < 4096; i += 256) {
    int r = i >> 6, c = i & 63;
    t[r][c] = src[(size_t)(r0 + r) * C + c0 + c];
  }
  __syncthreads();
#pragma unroll
  for (int i = threadIdx.x; i < 4096; i += 256) {
    int c = i >> 6, r = i & 63;
    dst[(size_t)(c0 + c) * R + r0 + r] = __float2bfloat16(t[r][c]);
  }
}

// ---------------- GEMM: C[M][N] = A[M][K] * Bt[N][K]^T ----------------
template <int EPI>
__global__ __launch_bounds__(256) void gemm_kernel(
    const bf16* __restrict__ A, const bf16* __restrict__ Bt,
    int M, int N, int K, int ntn,
    const float* __restrict__ bq, const float* __restrict__ bk,
    const float* __restrict__ bv,
    bf16* __restrict__ Qb, bf16* __restrict__ Kb, bf16* __restrict__ Vt,
    const float* __restrict__ bo, float* __restrict__ outp) {
  __shared__ bf16 sA[2][128 * 32];
  __shared__ bf16 sB[2][128 * 32];
  __shared__ bf16 strans[4][16][20];

  int bid = blockIdx.x;
  int bm = bid / ntn, bn = bid - bm * ntn;
  int tid = threadIdx.x;
  int w = tid >> 6, l = tid & 63;
  int wr = w >> 1, wc = w & 1;
  int l15 = l & 15, g = l >> 4;

  const bf16* Ab = A + (size_t)bm * 128 * K;
  const bf16* Bb = Bt + (size_t)bn * 128 * K;

  int sr = tid >> 2;              // staging row 0..63
  int sc = (tid & 3) << 3;        // staging col (elems)

  f32x4 acc[4][4] = {};
  int NT = K >> 5;
  int cur = 0;

  auto stage = [&](int buf, int kt) {
    const bf16* ga = Ab + (size_t)sr * K + kt * 32 + sc;
    const bf16* gb = Bb + (size_t)sr * K + kt * 32 + sc;
    bf16* la = &sA[buf][w << 9];
    bf16* lb = &sB[buf][w << 9];
    gload_lds16(ga, la);
    gload_lds16(ga + (size_t)64 * K, la + 2048);
    gload_lds16(gb, lb);
    gload_lds16(gb + (size_t)64 * K, lb + 2048);
  };

  stage(0, 0);
  for (int kt = 0; kt < NT; ++kt) {
    __syncthreads();
    if (kt + 1 < NT) stage(cur ^ 1, kt + 1);
    const bf16* pa = &sA[cur][0];
    const bf16* pb = &sB[cur][0];
    bf16x8 af[4], bfr[4];
#pragma unroll
    for (int m = 0; m < 4; ++m)
      af[m] = *(const bf16x8*)&pa[(wr * 64 + m * 16 + l15) * 32 + g * 8];
#pragma unroll
    for (int n = 0; n < 4; ++n)
      bfr[n] = *(const bf16x8*)&pb[(wc * 64 + n * 16 + l15) * 32 + g * 8];
#pragma unroll
    for (int m = 0; m < 4; ++m)
#pragma unroll
      for (int n = 0; n < 4; ++n)
        acc[m][n] = __builtin_amdgcn_mfma_f32_16x16x32_bf16(af[m], bfr[n], acc[m][n], 0, 0, 0);
    cur ^= 1;
  }

  if (EPI == 0) {
#pragma unroll
    for (int n = 0; n < 4; ++n) {
      int j = bn * 128 + wc * 64 + n * 16 + l15;
      int mat = j / 768;
      int jj = j - mat * 768;
      int h = jj >> 6, e = jj & 63;
      const float* bias = (mat == 0) ? bq : (mat == 1) ? bk : bv;
      float bb = bias[h * 64 + e];
      float scl = (mat == 0) ? QSCALE : 1.0f;   // Q pre-scaled into exp2 domain
#pragma unroll
      for (int m = 0; m < 4; ++m) {
        int s0m = bm * 128 + wr * 64 + m * 16;
        if (mat < 2) {
          bf16* dst = (mat == 0 ? Qb : Kb) + (size_t)h * SEQ * 64;
#pragma unroll
          for (int r = 0; r < 4; ++r)
            dst[(size_t)(s0m + g * 4 + r) * 64 + e] = __float2bfloat16((acc[m][n][r] + bb) * scl);
        } else {
#pragma unroll
          for (int r = 0; r < 4; ++r)
            strans[w][g * 4 + r][l15] = __float2bfloat16(acc[m][n][r] + bb);
          int e0f = e - l15;
          bf16* dst = Vt + (size_t)h * SEQ * 64;
#pragma unroll
          for (int r = 0; r < 4; ++r) {
            bf16 val = strans[w][l15][g * 4 + r];
            dst[(size_t)(e0f + g * 4 + r) * SEQ + s0m + l15] = val;
          }
        }
      }
    }
  } else {
#pragma unroll
    for (int n = 0; n < 4; ++n) {
      int j = bn * 128 + wc * 64 + n * 16 + l15;
      float bb = bo[j];
#pragma unroll
      for (int m = 0; m < 4; ++m) {
        int s0m = bm * 128 + wr * 64 + m * 16;
#pragma unroll
        for (int r = 0; r < 4; ++r)
          outp[(size_t)(s0m + g * 4 + r) * HIDDEN + j] = acc[m][n][r] + bb;
      }
    }
  }
}

// ---------------- flash attention v4: swapped QK^T, in-register P ----------------
// grid (SEQ/64, HEADS) = 768 blocks (3/CU), 256 threads, 16 q-rows/wave.
// mfma(K,Q) puts the q-row lane-local: row-max = 15 local fmax + 2 shuffles;
// P packed via v_cvt_pk_bf16_f32 and routed into PV A-frags with
// v_permlane32_swap_b32 + xor16 shuffles + cndmask (no LDS round trip).
__global__ __launch_bounds__(256) void flash_kernel(
    const bf16* __restrict__ Qb, const bf16* __restrict__ Kb,
    const bf16* __restrict__ Vt, bf16* __restrict__ ctx) {
  __shared__ bf16 sK[2][64 * 64];   // [t][e], 128B rows, swizzled
  __shared__ bf16 sV[2][64 * 64];   // [e][t], 128B rows, swizzled

  const int head = blockIdx.y;
  const int w = threadIdx.x >> 6, l = threadIdx.x & 63;
  const int l15 = l & 15, g = l >> 4;
  const int sw = l15 & 7;
  const int q0w = blockIdx.x * 64 + w * 16;

  const bf16* Qh = Qb + (size_t)head * SEQ * 64;
  const bf16* Kh = Kb + (size_t)head * SEQ * 64;
  const bf16* Vh = Vt + (size_t)head * SEQ * 64;   // [64][SEQ]

  // Q as B-operand: lane holds Q[col=q0w+l15][k-slice g]
  bf16x8 aq[2];
  aq[0] = *(const bf16x8*)&Qh[(size_t)(q0w + l15) * 64 + g * 8];
  aq[1] = *(const bf16x8*)&Qh[(size_t)(q0w + l15) * 64 + 32 + g * 8];

  float mrun = -1e30f, lsum = 0.f;   // scalar per lane (its q-row = l15)
  f32x4 cacc[4] = {};

  const int lr8 = l >> 3;            // row-in-call 0..7
  const int csrc = (l & 7) ^ lr8;    // pre-swizzled source chunk

  auto stage = [&](int buf, int kt) {
    int t0 = kt * 64;
    const bf16* gk = Kh + (size_t)(t0 + w * 16 + lr8) * 64 + csrc * 8;
    bf16* lk = &sK[buf][(w * 16) * 64];
    gload_lds16(gk, lk);
    gload_lds16(gk + (size_t)8 * 64, lk + 8 * 64);
    const bf16* gv = Vh + (size_t)(w * 16 + lr8) * SEQ + t0 + csrc * 8;
    bf16* lv = &sV[buf][(w * 16) * 64];
    gload_lds16(gv, lv);
    gload_lds16(gv + (size_t)8 * SEQ, lv + 8 * 64);
  };

  stage(0, 0);
  int cur = 0;
  const bool ge = (l & 16) == 0;     // g even

  for (int kt = 0; kt < SEQ / 64; ++kt) {
    __syncthreads();               // drains prev stage (vmcnt) + protects buffers
    if (kt + 1 < SEQ / 64) stage(cur ^ 1, kt + 1);
    const bf16* kb = &sK[cur][0];
    const bf16* vb = &sV[cur][0];

    // ---- S^T = K·Q^T: lane holds S[t=n*16+g*4+r][q=l15] ----
    f32x4 sc8[4] = {};
    __builtin_amdgcn_s_setprio(1);
#pragma unroll
    for (int n = 0; n < 4; ++n) {
      bf16x8 b0 = *(const bf16x8*)&kb[(n * 16 + l15) * 64 + (g ^ sw) * 8];
      bf16x8 b1 = *(const bf16x8*)&kb[(n * 16 + l15) * 64 + ((4 + g) ^ sw) * 8];
      sc8[n] = __builtin_amdgcn_mfma_f32_16x16x32_bf16(b0, aq[0], sc8[n], 0, 0, 0);
      sc8[n] = __builtin_amdgcn_mfma_f32_16x16x32_bf16(b1, aq[1], sc8[n], 0, 0, 0);
    }
    __builtin_amdgcn_s_setprio(0);

    // ---- row-max: 15 local fmax + 2 cross-g shuffles ----
    float vm = fmaxf(fmaxf(fmaxf(sc8[0][0], sc8[0][1]), fmaxf(sc8[0][2], sc8[0][3])),
                     fmaxf(fmaxf(sc8[1][0], sc8[1][1]), fmaxf(sc8[1][2], sc8[1][3])));
    vm = fmaxf(vm, fmaxf(fmaxf(fmaxf(sc8[2][0], sc8[2][1]), fmaxf(sc8[2][2], sc8[2][3])),
                         fmaxf(fmaxf(sc8[3][0], sc8[3][1]), fmaxf(sc8[3][2], sc8[3][3]))));
    vm = fmaxf(vm, __shfl_xor(vm, 16));
    vm = fmaxf(vm, __shfl_xor(vm, 32));

    // ---- defer-rescale (THR=8 in log2 domain) ----
    if (__any(vm > mrun + 8.0f)) {
      float mn = fmaxf(mrun, vm);
      float a = __builtin_amdgcn_exp2f(mrun - mn);
      mrun = mn;
      lsum *= a;
      float aqr[4];
#pragma unroll
      for (int r = 0; r < 4; ++r) aqr[r] = __shfl(a, g * 4 + r);
#pragma unroll
      for (int f = 0; f < 4; ++f)
#pragma unroll
        for (int r = 0; r < 4; ++r) cacc[f][r] *= aqr[r];
    }

    // ---- P = exp2(S - m), packed in-register ----
    unsigned X[4][2];
    float ls0 = 0.f, ls1 = 0.f;
#pragma unroll
    for (int n = 0; n < 4; ++n) {
#pragma unroll
      for (int h = 0; h < 2; ++h) {
        float p0 = __builtin_amdgcn_exp2f(sc8[n][2 * h] - mrun);
        float p1 = __builtin_amdgcn_exp2f(sc8[n][2 * h + 1] - mrun);
        ls0 += p0; ls1 += p1;
        X[n][h] = cvt_pk_bf16(p0, p1);
      }
    }
    lsum += ls0 + ls1;

    // ---- route packed P into PV A-frags + PV ----
#pragma unroll
    for (int kkl = 0; kkl < 2; ++kkl) {
      unsigned P0 = X[2 * kkl][0], Q0 = X[2 * kkl + 1][0];
      unsigned P1 = X[2 * kkl][1], Q1 = X[2 * kkl + 1][1];
      asm("v_permlane32_swap_b32 %0, %1" : "+v"(P0), "+v"(Q0));
      asm("v_permlane32_swap_b32 %0, %1" : "+v"(P1), "+v"(Q1));
      unsigned sP0 = __shfl_xor((int)P0, 16);
      unsigned sQ0 = __shfl_xor((int)Q0, 16);
      unsigned sP1 = __shfl_xor((int)P1, 16);
      unsigned sQ1 = __shfl_xor((int)Q1, 16);
      union { unsigned u[4]; bf16x8 v8; } ap;
      ap.u[0] = ge ? P0 : sQ0;
      ap.u[1] = ge ? P1 : sQ1;
      ap.u[2] = ge ? sP0 : Q0;
      ap.u[3] = ge ? sP1 : Q1;
      __builtin_amdgcn_s_setprio(1);
#pragma unroll
      for (int f = 0; f < 4; ++f) {
        bf16x8 bv8 = *(const bf16x8*)&vb[(f * 16 + l15) * 64 + ((kkl * 4 + g) ^ sw) * 8];
        cacc[f] = __builtin_amdgcn_mfma_f32_16x16x32_bf16(ap.v8, bv8, cacc[f], 0, 0, 0);
      }
      __builtin_amdgcn_s_setprio(0);
    }
    cur ^= 1;
  }

  // ---- epilogue: l reduce across g, redistribute inv, store ----
  float s = lsum;
  s += __shfl_xor(s, 16);
  s += __shfl_xor(s, 32);
  float inv = 1.0f / s;
  float invq[4];
#pragma unroll
  for (int r = 0; r < 4; ++r) invq[r] = __shfl(inv, g * 4 + r);
#pragma unroll
  for (int f = 0; f < 4; ++f)
#pragma unroll
    for (int r = 0; r < 4; ++r)
      ctx[(size_t)(q0w + g * 4 + r) * HIDDEN + head * 64 + f * 16 + l15] =
          __float2bfloat16(cacc[f][r] * invq[r]);
}

// ---------------- launcher ----------------
extern "C" void kernel_launch(void* const* d_in, const int* in_sizes, int n_in,
                              void* d_out, int out_size, void* d_ws, size_t ws_size,
                              hipStream_t stream) {
  const float* x = (const float*)d_in[0];
  const float* Wq = (const float*)d_in[1];
  const float* Wk = (const float*)d_in[2];
  const float* Wv = (const float*)d_in[3];
  const float* bq = (const float*)d_in[4];
  const float* bk = (const float*)d_in[5];
  const float* bv = (const float*)d_in[6];
  const float* Wo = (const float*)d_in[7];
  const float* bo = (const float*)d_in[8];
  float* outp = (float*)d_out;

  char* ws = (char*)d_ws;
  bf16* xb = (bf16*)ws;   ws += (size_t)SEQ * HIDDEN * 2;
  bf16* Wt = (bf16*)ws;   ws += (size_t)3 * HIDDEN * HIDDEN * 2;
  bf16* Wot = (bf16*)ws;  ws += (size_t)HIDDEN * HIDDEN * 2;
  bf16* Qb = (bf16*)ws;   ws += (size_t)SEQ * HIDDEN * 2;
  bf16* Kb = (bf16*)ws;   ws += (size_t)SEQ * HIDDEN * 2;
  bf16* Vt = (bf16*)ws;   ws += (size_t)SEQ * HIDDEN * 2;
  bf16* ctx = (bf16*)ws;  ws += (size_t)SEQ * HIDDEN * 2;

  cvt_x_kernel<<<SEQ * HIDDEN / 4 / 256, 256, 0, stream>>>(x, xb);
  tconv_kernel<<<dim3(12, 12), 256, 0, stream>>>(Wq, Wt, 768, 64);
  tconv_kernel<<<dim3(12, 12), 256, 0, stream>>>(Wk, Wt + 589824, 768, 64);
  tconv_kernel<<<dim3(12, 12), 256, 0, stream>>>(Wv, Wt + 2 * 589824, 768, 64);
  tconv_kernel<<<dim3(144, 1), 256, 0, stream>>>(Wo, Wot, 768, 768);

  gemm_kernel<0><<<32 * 18, 256, 0, stream>>>(xb, Wt, SEQ, 2304, 768, 18,
                                              bq, bk, bv, Qb, Kb, Vt, nullptr, nullptr);

  flash_kernel<<<dim3(64, 12), 256, 0, stream>>>(Qb, Kb, Vt, ctx);

  gemm_kernel<1><<<32 * 6, 256, 0, stream>>>(ctx, Wot, SEQ, 768, 768, 6,
                                             nullptr, nullptr, nullptr, nullptr, nullptr,
                                             nullptr, bo, outp);
}

// Round 6
// 162.369 us; speedup vs baseline: 2.6464x; 1.1144x over previous
//
#include <hip/hip_runtime.h>
#include <hip/hip_bf16.h>
#include <cstdint>
#include <cstddef>

#define HIDDEN 768
#define HEADS 12
#define HD 64
#define SEQ 4096
#define NSPLIT 2

typedef __hip_bfloat16 bf16;
typedef short bf16x8 __attribute__((ext_vector_type(8)));
typedef float f32x4 __attribute__((ext_vector_type(4)));

// 0.125 (1/sqrt(64)) * log2(e): folded into Q so softmax runs in exp2 domain
#define QSCALE 0.18033688011112042f

static __device__ __forceinline__ void gload_lds16(const bf16* g, bf16* l) {
  __builtin_amdgcn_global_load_lds(
      (const __attribute__((address_space(1))) unsigned int*)(g),
      (__attribute__((address_space(3))) unsigned int*)(l), 16, 0, 0);
}

static __device__ __forceinline__ unsigned cvt_pk_bf16(float lo, float hi) {
  unsigned r;
  asm("v_cvt_pk_bf16_f32 %0, %1, %2" : "=v"(r) : "v"(lo), "v"(hi));
  return r;
}

// ---------------- conversion kernels ----------------

__global__ void cvt_x_kernel(const float* __restrict__ in, bf16* __restrict__ outb) {
  int i = blockIdx.x * 256 + threadIdx.x;   // one float4 per thread
  float4 v = ((const float4*)in)[i];
  union { bf16 h[4]; short4 s4; } u;
  u.h[0] = __float2bfloat16(v.x);
  u.h[1] = __float2bfloat16(v.y);
  u.h[2] = __float2bfloat16(v.z);
  u.h[3] = __float2bfloat16(v.w);
  ((short4*)outb)[i] = u.s4;
}

// batched transpose+convert: in = batch x [R][C] f32 -> out = batch x [C][R] bf16
__global__ void tconv_kernel(const float* __restrict__ in, bf16* __restrict__ outb,
                             int R, int C) {
  int b = blockIdx.y;
  int tiles_c = C >> 6;
  int tr = blockIdx.x / tiles_c;
  int tc = blockIdx.x - tr * tiles_c;
  __shared__ float t[64][65];
  const float* src = in + (size_t)b * R * C;
  bf16* dst = outb + (size_t)b * R * C;
  int r0 = tr << 6, c0 = tc << 6;
#pragma unroll
  for (int i = threadIdx.x; i < 4096; i += 256) {
    int r = i >> 6, c = i & 63;
    t[r][c] = src[(size_t)(r0 + r) * C + c0 + c];
  }
  __syncthreads();
#pragma unroll
  for (int i = threadIdx.x; i < 4096; i += 256) {
    int c = i >> 6, r = i & 63;
    dst[(size_t)(c0 + c) * R + r0 + r] = __float2bfloat16(t[r][c]);
  }
}

// ---------------- GEMM: C[M][N] = A[M][K] * Bt[N][K]^T ----------------
template <int EPI>
__global__ __launch_bounds__(256) void gemm_kernel(
    const bf16* __restrict__ A, const bf16* __restrict__ Bt,
    int M, int N, int K, int ntn,
    const float* __restrict__ bq, const float* __restrict__ bk,
    const float* __restrict__ bv,
    bf16* __restrict__ Qb, bf16* __restrict__ Kb, bf16* __restrict__ Vt,
    const float* __restrict__ bo, float* __restrict__ outp) {
  __shared__ bf16 sA[2][128 * 32];
  __shared__ bf16 sB[2][128 * 32];
  __shared__ bf16 strans[4][16][20];

  int bid = blockIdx.x;
  int bm = bid / ntn, bn = bid - bm * ntn;
  int tid = threadIdx.x;
  int w = tid >> 6, l = tid & 63;
  int wr = w >> 1, wc = w & 1;
  int l15 = l & 15, g = l >> 4;

  const bf16* Ab = A + (size_t)bm * 128 * K;
  const bf16* Bb = Bt + (size_t)bn * 128 * K;

  int sr = tid >> 2;              // staging row 0..63
  int sc = (tid & 3) << 3;        // staging col (elems)

  f32x4 acc[4][4] = {};
  int NT = K >> 5;
  int cur = 0;

  auto stage = [&](int buf, int kt) {
    const bf16* ga = Ab + (size_t)sr * K + kt * 32 + sc;
    const bf16* gb = Bb + (size_t)sr * K + kt * 32 + sc;
    bf16* la = &sA[buf][w << 9];
    bf16* lb = &sB[buf][w << 9];
    gload_lds16(ga, la);
    gload_lds16(ga + (size_t)64 * K, la + 2048);
    gload_lds16(gb, lb);
    gload_lds16(gb + (size_t)64 * K, lb + 2048);
  };

  stage(0, 0);
  for (int kt = 0; kt < NT; ++kt) {
    __syncthreads();
    if (kt + 1 < NT) stage(cur ^ 1, kt + 1);
    const bf16* pa = &sA[cur][0];
    const bf16* pb = &sB[cur][0];
    bf16x8 af[4], bfr[4];
#pragma unroll
    for (int m = 0; m < 4; ++m)
      af[m] = *(const bf16x8*)&pa[(wr * 64 + m * 16 + l15) * 32 + g * 8];
#pragma unroll
    for (int n = 0; n < 4; ++n)
      bfr[n] = *(const bf16x8*)&pb[(wc * 64 + n * 16 + l15) * 32 + g * 8];
#pragma unroll
    for (int m = 0; m < 4; ++m)
#pragma unroll
      for (int n = 0; n < 4; ++n)
        acc[m][n] = __builtin_amdgcn_mfma_f32_16x16x32_bf16(af[m], bfr[n], acc[m][n], 0, 0, 0);
    cur ^= 1;
  }

  if (EPI == 0) {
#pragma unroll
    for (int n = 0; n < 4; ++n) {
      int j = bn * 128 + wc * 64 + n * 16 + l15;
      int mat = j / 768;
      int jj = j - mat * 768;
      int h = jj >> 6, e = jj & 63;
      const float* bias = (mat == 0) ? bq : (mat == 1) ? bk : bv;
      float bb = bias[h * 64 + e];
      float scl = (mat == 0) ? QSCALE : 1.0f;   // Q pre-scaled into exp2 domain
#pragma unroll
      for (int m = 0; m < 4; ++m) {
        int s0m = bm * 128 + wr * 64 + m * 16;
        if (mat < 2) {
          bf16* dst = (mat == 0 ? Qb : Kb) + (size_t)h * SEQ * 64;
#pragma unroll
          for (int r = 0; r < 4; ++r)
            dst[(size_t)(s0m + g * 4 + r) * 64 + e] = __float2bfloat16((acc[m][n][r] + bb) * scl);
        } else {
#pragma unroll
          for (int r = 0; r < 4; ++r)
            strans[w][g * 4 + r][l15] = __float2bfloat16(acc[m][n][r] + bb);
          int e0f = e - l15;
          bf16* dst = Vt + (size_t)h * SEQ * 64;
#pragma unroll
          for (int r = 0; r < 4; ++r) {
            bf16 val = strans[w][l15][g * 4 + r];
            dst[(size_t)(e0f + g * 4 + r) * SEQ + s0m + l15] = val;
          }
        }
      }
    }
  } else {
#pragma unroll
    for (int n = 0; n < 4; ++n) {
      int j = bn * 128 + wc * 64 + n * 16 + l15;
      float bb = bo[j];
#pragma unroll
      for (int m = 0; m < 4; ++m) {
        int s0m = bm * 128 + wr * 64 + m * 16;
#pragma unroll
        for (int r = 0; r < 4; ++r)
          outp[(size_t)(s0m + g * 4 + r) * HIDDEN + j] = acc[m][n][r] + bb;
      }
    }
  }
}

// ---------------- flash attention v5: split-KV, 8-wave blocks ----------------
// grid (SEQ/128, HEADS, NSPLIT) = 768 blocks x 8 waves = 6 waves/SIMD.
// Each block: 128 q-rows (16/wave), K-range [split*SEQ/2, ...+SEQ/2).
// Writes unnormalized f32 partials + per-row (m,l); combine_kernel merges.
__global__ __launch_bounds__(512) void flash_kernel(
    const bf16* __restrict__ Qb, const bf16* __restrict__ Kb,
    const bf16* __restrict__ Vt, float* __restrict__ partC,
    float* __restrict__ partM, float* __restrict__ partL) {
  __shared__ bf16 sK[2][64 * 64];   // [t][e], 128B rows, swizzled
  __shared__ bf16 sV[2][64 * 64];   // [e][t], 128B rows, swizzled

  const int head = blockIdx.y;
  const int split = blockIdx.z;
  const int w = threadIdx.x >> 6, l = threadIdx.x & 63;
  const int l15 = l & 15, g = l >> 4;
  const int sw = l15 & 7;
  const int q0w = blockIdx.x * 128 + w * 16;

  const bf16* Qh = Qb + (size_t)head * SEQ * 64;
  const bf16* Kh = Kb + (size_t)head * SEQ * 64;
  const bf16* Vh = Vt + (size_t)head * SEQ * 64;   // [64][SEQ]

  // Q as B-operand: lane holds Q[col=q0w+l15][k-slice g]
  bf16x8 aq[2];
  aq[0] = *(const bf16x8*)&Qh[(size_t)(q0w + l15) * 64 + g * 8];
  aq[1] = *(const bf16x8*)&Qh[(size_t)(q0w + l15) * 64 + 32 + g * 8];

  float mrun = -1e30f, lsum = 0.f;   // scalar per lane (its q-row = l15)
  f32x4 cacc[4] = {};

  const int lr8 = l >> 3;            // row-in-call 0..7
  const int csrc = (l & 7) ^ lr8;    // pre-swizzled source chunk

  // wave w stages K rows [w*8, w*8+8) and V rows [w*8, w*8+8)
  auto stage = [&](int buf, int kt) {
    int t0 = kt * 64;
    const bf16* gk = Kh + (size_t)(t0 + w * 8 + lr8) * 64 + csrc * 8;
    gload_lds16(gk, &sK[buf][(w * 8) * 64]);
    const bf16* gv = Vh + (size_t)(w * 8 + lr8) * SEQ + t0 + csrc * 8;
    gload_lds16(gv, &sV[buf][(w * 8) * 64]);
  };

  const int kt0 = split * (SEQ / 64 / NSPLIT);
  const int kt1 = kt0 + SEQ / 64 / NSPLIT;
  stage(0, kt0);
  int cur = 0;
  const bool ge = (l & 16) == 0;     // g even

  for (int kt = kt0; kt < kt1; ++kt) {
    __syncthreads();               // drains prev stage (vmcnt) + protects buffers
    if (kt + 1 < kt1) stage(cur ^ 1, kt + 1);
    const bf16* kb = &sK[cur][0];
    const bf16* vb = &sV[cur][0];

    // ---- S^T = K·Q^T: lane holds S[t=n*16+g*4+r][q=l15] ----
    f32x4 sc8[4] = {};
    __builtin_amdgcn_s_setprio(1);
#pragma unroll
    for (int n = 0; n < 4; ++n) {
      bf16x8 b0 = *(const bf16x8*)&kb[(n * 16 + l15) * 64 + (g ^ sw) * 8];
      bf16x8 b1 = *(const bf16x8*)&kb[(n * 16 + l15) * 64 + ((4 + g) ^ sw) * 8];
      sc8[n] = __builtin_amdgcn_mfma_f32_16x16x32_bf16(b0, aq[0], sc8[n], 0, 0, 0);
      sc8[n] = __builtin_amdgcn_mfma_f32_16x16x32_bf16(b1, aq[1], sc8[n], 0, 0, 0);
    }
    __builtin_amdgcn_s_setprio(0);

    // ---- row-max: 15 local fmax + 2 cross-g shuffles ----
    float vm = fmaxf(fmaxf(fmaxf(sc8[0][0], sc8[0][1]), fmaxf(sc8[0][2], sc8[0][3])),
                     fmaxf(fmaxf(sc8[1][0], sc8[1][1]), fmaxf(sc8[1][2], sc8[1][3])));
    vm = fmaxf(vm, fmaxf(fmaxf(fmaxf(sc8[2][0], sc8[2][1]), fmaxf(sc8[2][2], sc8[2][3])),
                         fmaxf(fmaxf(sc8[3][0], sc8[3][1]), fmaxf(sc8[3][2], sc8[3][3]))));
    vm = fmaxf(vm, __shfl_xor(vm, 16));
    vm = fmaxf(vm, __shfl_xor(vm, 32));

    // ---- defer-rescale (THR=8 in log2 domain) ----
    if (__any(vm > mrun + 8.0f)) {
      float mn = fmaxf(mrun, vm);
      float a = __builtin_amdgcn_exp2f(mrun - mn);
      mrun = mn;
      lsum *= a;
      float aqr[4];
#pragma unroll
      for (int r = 0; r < 4; ++r) aqr[r] = __shfl(a, g * 4 + r);
#pragma unroll
      for (int f = 0; f < 4; ++f)
#pragma unroll
        for (int r = 0; r < 4; ++r) cacc[f][r] *= aqr[r];
    }

    // ---- P = exp2(S - m), packed in-register ----
    unsigned X[4][2];
    float ls0 = 0.f, ls1 = 0.f;
#pragma unroll
    for (int n = 0; n < 4; ++n) {
#pragma unroll
      for (int h = 0; h < 2; ++h) {
        float p0 = __builtin_amdgcn_exp2f(sc8[n][2 * h] - mrun);
        float p1 = __builtin_amdgcn_exp2f(sc8[n][2 * h + 1] - mrun);
        ls0 += p0; ls1 += p1;
        X[n][h] = cvt_pk_bf16(p0, p1);
      }
    }
    lsum += ls0 + ls1;

    // ---- route packed P into PV A-frags + PV ----
#pragma unroll
    for (int kkl = 0; kkl < 2; ++kkl) {
      unsigned P0 = X[2 * kkl][0], Q0 = X[2 * kkl + 1][0];
      unsigned P1 = X[2 * kkl][1], Q1 = X[2 * kkl + 1][1];
      asm("v_permlane32_swap_b32 %0, %1" : "+v"(P0), "+v"(Q0));
      asm("v_permlane32_swap_b32 %0, %1" : "+v"(P1), "+v"(Q1));
      unsigned sP0 = __shfl_xor((int)P0, 16);
      unsigned sQ0 = __shfl_xor((int)Q0, 16);
      unsigned sP1 = __shfl_xor((int)P1, 16);
      unsigned sQ1 = __shfl_xor((int)Q1, 16);
      union { unsigned u[4]; bf16x8 v8; } ap;
      ap.u[0] = ge ? P0 : sQ0;
      ap.u[1] = ge ? P1 : sQ1;
      ap.u[2] = ge ? sP0 : Q0;
      ap.u[3] = ge ? sP1 : Q1;
      __builtin_amdgcn_s_setprio(1);
#pragma unroll
      for (int f = 0; f < 4; ++f) {
        bf16x8 bv8 = *(const bf16x8*)&vb[(f * 16 + l15) * 64 + ((kkl * 4 + g) ^ sw) * 8];
        cacc[f] = __builtin_amdgcn_mfma_f32_16x16x32_bf16(ap.v8, bv8, cacc[f], 0, 0, 0);
      }
      __builtin_amdgcn_s_setprio(0);
    }
    cur ^= 1;
  }

  // ---- epilogue: reduce l across g, write unnormalized partials ----
  float s = lsum;
  s += __shfl_xor(s, 16);
  s += __shfl_xor(s, 32);

  float* pcw = partC + (size_t)split * SEQ * HIDDEN;
#pragma unroll
  for (int f = 0; f < 4; ++f)
#pragma unroll
    for (int r = 0; r < 4; ++r)
      pcw[(size_t)(q0w + g * 4 + r) * HIDDEN + head * 64 + f * 16 + l15] = cacc[f][r];
  if (l < 16) {
    size_t mi = (size_t)split * HEADS * SEQ + (size_t)head * SEQ + q0w + l15;
    partM[mi] = mrun;
    partL[mi] = s;
  }
}

// ---------------- split-KV combine ----------------
__global__ __launch_bounds__(256) void combine_kernel(
    const float* __restrict__ partC, const float* __restrict__ partM,
    const float* __restrict__ partL, bf16* __restrict__ ctx) {
  int i = blockIdx.x * 256 + threadIdx.x;   // one float4 (4 elems) per thread
  int idx = i * 4;
  int s = idx / HIDDEN, c = idx - s * HIDDEN;
  int h = c >> 6;
  size_t mi = (size_t)h * SEQ + s;
  float m0 = partM[mi], m1 = partM[(size_t)HEADS * SEQ + mi];
  float l0 = partL[mi], l1 = partL[(size_t)HEADS * SEQ + mi];
  float ms = fmaxf(m0, m1);
  float w0 = __builtin_amdgcn_exp2f(m0 - ms);
  float w1 = __builtin_amdgcn_exp2f(m1 - ms);
  float inv = 1.0f / (l0 * w0 + l1 * w1);
  float4 c0 = ((const float4*)partC)[i];
  float4 c1 = ((const float4*)(partC + (size_t)SEQ * HIDDEN))[i];
  union { bf16 h4[4]; short4 s4; } u;
  u.h4[0] = __float2bfloat16((c0.x * w0 + c1.x * w1) * inv);
  u.h4[1] = __float2bfloat16((c0.y * w0 + c1.y * w1) * inv);
  u.h4[2] = __float2bfloat16((c0.z * w0 + c1.z * w1) * inv);
  u.h4[3] = __float2bfloat16((c0.w * w0 + c1.w * w1) * inv);
  ((short4*)ctx)[i] = u.s4;
}

// ---------------- launcher ----------------
extern "C" void kernel_launch(void* const* d_in, const int* in_sizes, int n_in,
                              void* d_out, int out_size, void* d_ws, size_t ws_size,
                              hipStream_t stream) {
  const float* x = (const float*)d_in[0];
  const float* Wq = (const float*)d_in[1];
  const float* Wk = (const float*)d_in[2];
  const float* Wv = (const float*)d_in[3];
  const float* bq = (const float*)d_in[4];
  const float* bk = (const float*)d_in[5];
  const float* bv = (const float*)d_in[6];
  const float* Wo = (const float*)d_in[7];
  const float* bo = (const float*)d_in[8];
  float* outp = (float*)d_out;

  char* ws = (char*)d_ws;
  bf16* xb = (bf16*)ws;   ws += (size_t)SEQ * HIDDEN * 2;
  bf16* Wt = (bf16*)ws;   ws += (size_t)3 * HIDDEN * HIDDEN * 2;
  bf16* Wot = (bf16*)ws;  ws += (size_t)HIDDEN * HIDDEN * 2;
  bf16* Qb = (bf16*)ws;   ws += (size_t)SEQ * HIDDEN * 2;
  bf16* Kb = (bf16*)ws;   ws += (size_t)SEQ * HIDDEN * 2;
  bf16* Vt = (bf16*)ws;   ws += (size_t)SEQ * HIDDEN * 2;
  bf16* ctx = (bf16*)ws;  ws += (size_t)SEQ * HIDDEN * 2;
  float* partC = (float*)ws; ws += (size_t)NSPLIT * SEQ * HIDDEN * 4;
  float* partM = (float*)ws; ws += (size_t)NSPLIT * HEADS * SEQ * 4;
  float* partL = (float*)ws; ws += (size_t)NSPLIT * HEADS * SEQ * 4;

  cvt_x_kernel<<<SEQ * HIDDEN / 4 / 256, 256, 0, stream>>>(x, xb);
  tconv_kernel<<<dim3(12, 12), 256, 0, stream>>>(Wq, Wt, 768, 64);
  tconv_kernel<<<dim3(12, 12), 256, 0, stream>>>(Wk, Wt + 589824, 768, 64);
  tconv_kernel<<<dim3(12, 12), 256, 0, stream>>>(Wv, Wt + 2 * 589824, 768, 64);
  tconv_kernel<<<dim3(144, 1), 256, 0, stream>>>(Wo, Wot, 768, 768);

  gemm_kernel<0><<<32 * 18, 256, 0, stream>>>(xb, Wt, SEQ, 2304, 768, 18,
                                              bq, bk, bv, Qb, Kb, Vt, nullptr, nullptr);

  flash_kernel<<<dim3(SEQ / 128, HEADS, NSPLIT), 512, 0, stream>>>(Qb, Kb, Vt,
                                                                   partC, partM, partL);
  combine_kernel<<<SEQ * HIDDEN / 4 / 256, 256, 0, stream>>>(partC, partM, partL, ctx);

  gemm_kernel<1><<<32 * 6, 256, 0, stream>>>(ctx, Wot, SEQ, 768, 768, 6,
                                             nullptr, nullptr, nullptr, nullptr, nullptr,
                                             nullptr, bo, outp);
}

// Round 7
// 156.653 us; speedup vs baseline: 2.7430x; 1.0365x over previous
//
#include <hip/hip_runtime.h>
#include <hip/hip_bf16.h>
#include <cstdint>
#include <cstddef>

#define HIDDEN 768
#define HEADS 12
#define HD 64
#define SEQ 4096
#define NSPLIT 2

typedef __hip_bfloat16 bf16;
typedef short bf16x8 __attribute__((ext_vector_type(8)));
typedef float f32x4 __attribute__((ext_vector_type(4)));

// 0.125 (1/sqrt(64)) * log2(e): folded into Q so softmax runs in exp2 domain
#define QSCALE 0.18033688011112042f

static __device__ __forceinline__ void gload_lds16(const bf16* g, bf16* l) {
  __builtin_amdgcn_global_load_lds(
      (const __attribute__((address_space(1))) unsigned int*)(g),
      (__attribute__((address_space(3))) unsigned int*)(l), 16, 0, 0);
}

static __device__ __forceinline__ unsigned cvt_pk_bf16(float lo, float hi) {
  unsigned r;
  asm("v_cvt_pk_bf16_f32 %0, %1, %2" : "=v"(r) : "v"(lo), "v"(hi));
  return r;
}

// ---------------- fused prep: x->bf16 + all weight transposes ----------------
// grid: [0,3072) cvt_x; [3072,3504) Wq/Wk/Wv tiles; [3504,3648) Wo tiles.
__global__ __launch_bounds__(256) void prep_kernel(
    const float* __restrict__ x, const float* __restrict__ Wq,
    const float* __restrict__ Wk, const float* __restrict__ Wv,
    const float* __restrict__ Wo, bf16* __restrict__ xb,
    bf16* __restrict__ Wt, bf16* __restrict__ Wot) {
  __shared__ float t[64][65];
  int i = blockIdx.x;
  if (i < 3072) {
    int idx = i * 256 + threadIdx.x;
    float4 v = ((const float4*)x)[idx];
    union { bf16 h[4]; short4 s4; } u;
    u.h[0] = __float2bfloat16(v.x);
    u.h[1] = __float2bfloat16(v.y);
    u.h[2] = __float2bfloat16(v.z);
    u.h[3] = __float2bfloat16(v.w);
    ((short4*)xb)[idx] = u.s4;
    return;
  }
  i -= 3072;
  const float* src;
  bf16* dst;
  int R, C, tr, tc;
  if (i < 432) {                     // Wq/Wk/Wv: per-head [768][64] -> [64][768]
    int m = i / 144;
    int j = i - m * 144;
    int b = j / 12;
    tr = j - b * 12; tc = 0;
    src = (m == 0 ? Wq : m == 1 ? Wk : Wv) + (size_t)b * 768 * 64;
    dst = Wt + (size_t)m * 589824 + (size_t)b * 768 * 64;
    R = 768; C = 64;
  } else {                           // Wo: [768][768] -> [768][768]^T
    int j = i - 432;
    tr = j / 12; tc = j - tr * 12;
    src = Wo; dst = Wot; R = 768; C = 768;
  }
  int r0 = tr << 6, c0 = tc << 6;
#pragma unroll
  for (int k = threadIdx.x; k < 4096; k += 256) {
    int r = k >> 6, c = k & 63;
    t[r][c] = src[(size_t)(r0 + r) * C + c0 + c];
  }
  __syncthreads();
#pragma unroll
  for (int k = threadIdx.x; k < 4096; k += 256) {
    int c = k >> 6, r = k & 63;
    dst[(size_t)(c0 + c) * R + r0 + r] = __float2bfloat16(t[r][c]);
  }
}

// ---------------- GEMM: C[M][N] = A[M][K] * Bt[N][K]^T ----------------
template <int EPI>
__global__ __launch_bounds__(256) void gemm_kernel(
    const bf16* __restrict__ A, const bf16* __restrict__ Bt,
    int M, int N, int K, int ntn,
    const float* __restrict__ bq, const float* __restrict__ bk,
    const float* __restrict__ bv,
    bf16* __restrict__ Qb, bf16* __restrict__ Kb, bf16* __restrict__ Vt,
    const float* __restrict__ bo, float* __restrict__ outp) {
  __shared__ bf16 sA[2][128 * 32];
  __shared__ bf16 sB[2][128 * 32];
  __shared__ bf16 strans[4][16][20];

  int bid = blockIdx.x;
  int bm = bid / ntn, bn = bid - bm * ntn;
  int tid = threadIdx.x;
  int w = tid >> 6, l = tid & 63;
  int wr = w >> 1, wc = w & 1;
  int l15 = l & 15, g = l >> 4;

  const bf16* Ab = A + (size_t)bm * 128 * K;
  const bf16* Bb = Bt + (size_t)bn * 128 * K;

  int sr = tid >> 2;              // staging row 0..63
  int sc = (tid & 3) << 3;        // staging col (elems)

  f32x4 acc[4][4] = {};
  int NT = K >> 5;
  int cur = 0;

  auto stage = [&](int buf, int kt) {
    const bf16* ga = Ab + (size_t)sr * K + kt * 32 + sc;
    const bf16* gb = Bb + (size_t)sr * K + kt * 32 + sc;
    bf16* la = &sA[buf][w << 9];
    bf16* lb = &sB[buf][w << 9];
    gload_lds16(ga, la);
    gload_lds16(ga + (size_t)64 * K, la + 2048);
    gload_lds16(gb, lb);
    gload_lds16(gb + (size_t)64 * K, lb + 2048);
  };

  stage(0, 0);
  for (int kt = 0; kt < NT; ++kt) {
    __syncthreads();
    if (kt + 1 < NT) stage(cur ^ 1, kt + 1);
    const bf16* pa = &sA[cur][0];
    const bf16* pb = &sB[cur][0];
    bf16x8 af[4], bfr[4];
#pragma unroll
    for (int m = 0; m < 4; ++m)
      af[m] = *(const bf16x8*)&pa[(wr * 64 + m * 16 + l15) * 32 + g * 8];
#pragma unroll
    for (int n = 0; n < 4; ++n)
      bfr[n] = *(const bf16x8*)&pb[(wc * 64 + n * 16 + l15) * 32 + g * 8];
#pragma unroll
    for (int m = 0; m < 4; ++m)
#pragma unroll
      for (int n = 0; n < 4; ++n)
        acc[m][n] = __builtin_amdgcn_mfma_f32_16x16x32_bf16(af[m], bfr[n], acc[m][n], 0, 0, 0);
    cur ^= 1;
  }

  if (EPI == 0) {
#pragma unroll
    for (int n = 0; n < 4; ++n) {
      int j = bn * 128 + wc * 64 + n * 16 + l15;
      int mat = j / 768;
      int jj = j - mat * 768;
      int h = jj >> 6, e = jj & 63;
      const float* bias = (mat == 0) ? bq : (mat == 1) ? bk : bv;
      float bb = bias[h * 64 + e];
      float scl = (mat == 0) ? QSCALE : 1.0f;   // Q pre-scaled into exp2 domain
#pragma unroll
      for (int m = 0; m < 4; ++m) {
        int s0m = bm * 128 + wr * 64 + m * 16;
        if (mat < 2) {
          bf16* dst = (mat == 0 ? Qb : Kb) + (size_t)h * SEQ * 64;
#pragma unroll
          for (int r = 0; r < 4; ++r)
            dst[(size_t)(s0m + g * 4 + r) * 64 + e] = __float2bfloat16((acc[m][n][r] + bb) * scl);
        } else {
#pragma unroll
          for (int r = 0; r < 4; ++r)
            strans[w][g * 4 + r][l15] = __float2bfloat16(acc[m][n][r] + bb);
          int e0f = e - l15;
          bf16* dst = Vt + (size_t)h * SEQ * 64;
#pragma unroll
          for (int r = 0; r < 4; ++r) {
            bf16 val = strans[w][l15][g * 4 + r];
            dst[(size_t)(e0f + g * 4 + r) * SEQ + s0m + l15] = val;
          }
        }
      }
    }
  } else {
#pragma unroll
    for (int n = 0; n < 4; ++n) {
      int j = bn * 128 + wc * 64 + n * 16 + l15;
      float bb = bo[j];
#pragma unroll
      for (int m = 0; m < 4; ++m) {
        int s0m = bm * 128 + wr * 64 + m * 16;
#pragma unroll
        for (int r = 0; r < 4; ++r)
          outp[(size_t)(s0m + g * 4 + r) * HIDDEN + j] = acc[m][n][r] + bb;
      }
    }
  }
}

// ---------------- flash attention v6: split-KV + 1-tile lookahead pipeline ---
// grid (SEQ/128, HEADS, NSPLIT), 512 threads. 3 LDS buffers rotate:
// iter t: {barrier; stage(t+2)->C; QK(t+1)<-B; softmax(t); PV(t)<-A; rotate}.
// QK(t+1) MFMAs overlap softmax(t) VALU -> MFMA latency leaves the serial path.
__global__ __launch_bounds__(512) void flash_kernel(
    const bf16* __restrict__ Qb, const bf16* __restrict__ Kb,
    const bf16* __restrict__ Vt, float* __restrict__ partC,
    float* __restrict__ partM, float* __restrict__ partL) {
  __shared__ bf16 sK[3][64 * 64];   // [t][e], 128B rows, swizzled
  __shared__ bf16 sV[3][64 * 64];   // [e][t], 128B rows, swizzled

  const int head = blockIdx.y;
  const int split = blockIdx.z;
  const int w = threadIdx.x >> 6, l = threadIdx.x & 63;
  const int l15 = l & 15, g = l >> 4;
  const int sw = l15 & 7;
  const int q0w = blockIdx.x * 128 + w * 16;

  const bf16* Qh = Qb + (size_t)head * SEQ * 64;
  const bf16* Kh = Kb + (size_t)head * SEQ * 64;
  const bf16* Vh = Vt + (size_t)head * SEQ * 64;   // [64][SEQ]

  bf16x8 aq[2];
  aq[0] = *(const bf16x8*)&Qh[(size_t)(q0w + l15) * 64 + g * 8];
  aq[1] = *(const bf16x8*)&Qh[(size_t)(q0w + l15) * 64 + 32 + g * 8];

  float mrun = -1e30f, lsum = 0.f;   // scalar per lane (its q-row = l15)
  f32x4 cacc[4] = {};

  const int lr8 = l >> 3;            // row-in-call 0..7
  const int csrc = (l & 7) ^ lr8;    // pre-swizzled source chunk

  auto stage = [&](bf16* dk, bf16* dv, int kt) {
    int t0 = kt * 64;
    const bf16* gk = Kh + (size_t)(t0 + w * 8 + lr8) * 64 + csrc * 8;
    gload_lds16(gk, dk + (w * 8) * 64);
    const bf16* gv = Vh + (size_t)(w * 8 + lr8) * SEQ + t0 + csrc * 8;
    gload_lds16(gv, dv + (w * 8) * 64);
  };

  auto qk = [&](const bf16* kb, f32x4* sc) {
    __builtin_amdgcn_s_setprio(1);
#pragma unroll
    for (int n = 0; n < 4; ++n) {
      bf16x8 b0 = *(const bf16x8*)&kb[(n * 16 + l15) * 64 + (g ^ sw) * 8];
      bf16x8 b1 = *(const bf16x8*)&kb[(n * 16 + l15) * 64 + ((4 + g) ^ sw) * 8];
      sc[n] = __builtin_amdgcn_mfma_f32_16x16x32_bf16(b0, aq[0], sc[n], 0, 0, 0);
      sc[n] = __builtin_amdgcn_mfma_f32_16x16x32_bf16(b1, aq[1], sc[n], 0, 0, 0);
    }
    __builtin_amdgcn_s_setprio(0);
  };

  const int kt0 = split * (SEQ / 64 / NSPLIT);
  const int kt1 = kt0 + SEQ / 64 / NSPLIT;
  const bool ge = (l & 16) == 0;     // g even

  bf16 *kA = &sK[0][0], *vA = &sV[0][0];
  bf16 *kB = &sK[1][0], *vB = &sV[1][0];
  bf16 *kC = &sK[2][0], *vC = &sV[2][0];

  stage(kA, vA, kt0);
  if (kt0 + 1 < kt1) stage(kB, vB, kt0 + 1);
  __syncthreads();

  f32x4 sc_cur[4] = {};
  qk(kA, sc_cur);

  for (int t = kt0; t < kt1; ++t) {
    if (t > kt0) __syncthreads();      // gates staging + buffer reuse only
    if (t + 2 < kt1) stage(kC, vC, t + 2);

    f32x4 sc_nxt[4] = {};
    if (t + 1 < kt1) qk(kB, sc_nxt);   // overlaps softmax(t) below

    // ---- row-max of sc_cur: 15 local fmax + 2 cross-g shuffles ----
    float vm = fmaxf(fmaxf(fmaxf(sc_cur[0][0], sc_cur[0][1]), fmaxf(sc_cur[0][2], sc_cur[0][3])),
                     fmaxf(fmaxf(sc_cur[1][0], sc_cur[1][1]), fmaxf(sc_cur[1][2], sc_cur[1][3])));
    vm = fmaxf(vm, fmaxf(fmaxf(fmaxf(sc_cur[2][0], sc_cur[2][1]), fmaxf(sc_cur[2][2], sc_cur[2][3])),
                         fmaxf(fmaxf(sc_cur[3][0], sc_cur[3][1]), fmaxf(sc_cur[3][2], sc_cur[3][3]))));
    vm = fmaxf(vm, __shfl_xor(vm, 16));
    vm = fmaxf(vm, __shfl_xor(vm, 32));

    // ---- defer-rescale (THR=8 in log2 domain) ----
    if (__any(vm > mrun + 8.0f)) {
      float mn = fmaxf(mrun, vm);
      float a = __builtin_amdgcn_exp2f(mrun - mn);
      mrun = mn;
      lsum *= a;
      float aqr[4];
#pragma unroll
      for (int r = 0; r < 4; ++r) aqr[r] = __shfl(a, g * 4 + r);
#pragma unroll
      for (int f = 0; f < 4; ++f)
#pragma unroll
        for (int r = 0; r < 4; ++r) cacc[f][r] *= aqr[r];
    }

    // ---- P = exp2(S - m), packed in-register ----
    unsigned X[4][2];
    float ls0 = 0.f, ls1 = 0.f;
#pragma unroll
    for (int n = 0; n < 4; ++n) {
#pragma unroll
      for (int h = 0; h < 2; ++h) {
        float p0 = __builtin_amdgcn_exp2f(sc_cur[n][2 * h] - mrun);
        float p1 = __builtin_amdgcn_exp2f(sc_cur[n][2 * h + 1] - mrun);
        ls0 += p0; ls1 += p1;
        X[n][h] = cvt_pk_bf16(p0, p1);
      }
    }
    lsum += ls0 + ls1;

    // ---- route packed P into PV A-frags + PV from vA ----
#pragma unroll
    for (int kkl = 0; kkl < 2; ++kkl) {
      unsigned P0 = X[2 * kkl][0], Q0 = X[2 * kkl + 1][0];
      unsigned P1 = X[2 * kkl][1], Q1 = X[2 * kkl + 1][1];
      asm("v_permlane32_swap_b32 %0, %1" : "+v"(P0), "+v"(Q0));
      asm("v_permlane32_swap_b32 %0, %1" : "+v"(P1), "+v"(Q1));
      unsigned sP0 = __shfl_xor((int)P0, 16);
      unsigned sQ0 = __shfl_xor((int)Q0, 16);
      unsigned sP1 = __shfl_xor((int)P1, 16);
      unsigned sQ1 = __shfl_xor((int)Q1, 16);
      union { unsigned u[4]; bf16x8 v8; } ap;
      ap.u[0] = ge ? P0 : sQ0;
      ap.u[1] = ge ? P1 : sQ1;
      ap.u[2] = ge ? sP0 : Q0;
      ap.u[3] = ge ? sP1 : Q1;
      __builtin_amdgcn_s_setprio(1);
#pragma unroll
      for (int f = 0; f < 4; ++f) {
        bf16x8 bv8 = *(const bf16x8*)&vA[(f * 16 + l15) * 64 + ((kkl * 4 + g) ^ sw) * 8];
        cacc[f] = __builtin_amdgcn_mfma_f32_16x16x32_bf16(ap.v8, bv8, cacc[f], 0, 0, 0);
      }
      __builtin_amdgcn_s_setprio(0);
    }

    // rotate buffers; promote lookahead scores
    bf16* tk = kA; bf16* tv = vA;
    kA = kB; vA = vB;
    kB = kC; vB = vC;
    kC = tk; vC = tv;
#pragma unroll
    for (int n = 0; n < 4; ++n) sc_cur[n] = sc_nxt[n];
  }

  // ---- epilogue: reduce l across g, write unnormalized partials ----
  float s = lsum;
  s += __shfl_xor(s, 16);
  s += __shfl_xor(s, 32);

  float* pcw = partC + (size_t)split * SEQ * HIDDEN;
#pragma unroll
  for (int f = 0; f < 4; ++f)
#pragma unroll
    for (int r = 0; r < 4; ++r)
      pcw[(size_t)(q0w + g * 4 + r) * HIDDEN + head * 64 + f * 16 + l15] = cacc[f][r];
  if (l < 16) {
    size_t mi = (size_t)split * HEADS * SEQ + (size_t)head * SEQ + q0w + l15;
    partM[mi] = mrun;
    partL[mi] = s;
  }
}

// ---------------- split-KV combine ----------------
__global__ __launch_bounds__(256) void combine_kernel(
    const float* __restrict__ partC, const float* __restrict__ partM,
    const float* __restrict__ partL, bf16* __restrict__ ctx) {
  int i = blockIdx.x * 256 + threadIdx.x;   // one float4 (4 elems) per thread
  int idx = i * 4;
  int s = idx / HIDDEN, c = idx - s * HIDDEN;
  int h = c >> 6;
  size_t mi = (size_t)h * SEQ + s;
  float m0 = partM[mi], m1 = partM[(size_t)HEADS * SEQ + mi];
  float l0 = partL[mi], l1 = partL[(size_t)HEADS * SEQ + mi];
  float ms = fmaxf(m0, m1);
  float w0 = __builtin_amdgcn_exp2f(m0 - ms);
  float w1 = __builtin_amdgcn_exp2f(m1 - ms);
  float inv = 1.0f / (l0 * w0 + l1 * w1);
  float4 c0 = ((const float4*)partC)[i];
  float4 c1 = ((const float4*)(partC + (size_t)SEQ * HIDDEN))[i];
  union { bf16 h4[4]; short4 s4; } u;
  u.h4[0] = __float2bfloat16((c0.x * w0 + c1.x * w1) * inv);
  u.h4[1] = __float2bfloat16((c0.y * w0 + c1.y * w1) * inv);
  u.h4[2] = __float2bfloat16((c0.z * w0 + c1.z * w1) * inv);
  u.h4[3] = __float2bfloat16((c0.w * w0 + c1.w * w1) * inv);
  ((short4*)ctx)[i] = u.s4;
}

// ---------------- launcher ----------------
extern "C" void kernel_launch(void* const* d_in, const int* in_sizes, int n_in,
                              void* d_out, int out_size, void* d_ws, size_t ws_size,
                              hipStream_t stream) {
  const float* x = (const float*)d_in[0];
  const float* Wq = (const float*)d_in[1];
  const float* Wk = (const float*)d_in[2];
  const float* Wv = (const float*)d_in[3];
  const float* bq = (const float*)d_in[4];
  const float* bk = (const float*)d_in[5];
  const float* bv = (const float*)d_in[6];
  const float* Wo = (const float*)d_in[7];
  const float* bo = (const float*)d_in[8];
  float* outp = (float*)d_out;

  char* ws = (char*)d_ws;
  bf16* xb = (bf16*)ws;   ws += (size_t)SEQ * HIDDEN * 2;
  bf16* Wt = (bf16*)ws;   ws += (size_t)3 * HIDDEN * HIDDEN * 2;
  bf16* Wot = (bf16*)ws;  ws += (size_t)HIDDEN * HIDDEN * 2;
  bf16* Qb = (bf16*)ws;   ws += (size_t)SEQ * HIDDEN * 2;
  bf16* Kb = (bf16*)ws;   ws += (size_t)SEQ * HIDDEN * 2;
  bf16* Vt = (bf16*)ws;   ws += (size_t)SEQ * HIDDEN * 2;
  bf16* ctx = (bf16*)ws;  ws += (size_t)SEQ * HIDDEN * 2;
  float* partC = (float*)ws; ws += (size_t)NSPLIT * SEQ * HIDDEN * 4;
  float* partM = (float*)ws; ws += (size_t)NSPLIT * HEADS * SEQ * 4;
  float* partL = (float*)ws; ws += (size_t)NSPLIT * HEADS * SEQ * 4;

  prep_kernel<<<3648, 256, 0, stream>>>(x, Wq, Wk, Wv, Wo, xb, Wt, Wot);

  gemm_kernel<0><<<32 * 18, 256, 0, stream>>>(xb, Wt, SEQ, 2304, 768, 18,
                                              bq, bk, bv, Qb, Kb, Vt, nullptr, nullptr);

  flash_kernel<<<dim3(SEQ / 128, HEADS, NSPLIT), 512, 0, stream>>>(Qb, Kb, Vt,
                                                                   partC, partM, partL);
  combine_kernel<<<SEQ * HIDDEN / 4 / 256, 256, 0, stream>>>(partC, partM, partL, ctx);

  gemm_kernel<1><<<32 * 6, 256, 0, stream>>>(ctx, Wot, SEQ, 768, 768, 6,
                                             nullptr, nullptr, nullptr, nullptr, nullptr,
                                             nullptr, bo, outp);
}

// Round 8
// 150.797 us; speedup vs baseline: 2.8495x; 1.0388x over previous
//
#include <hip/hip_runtime.h>
#include <hip/hip_bf16.h>
#include <cstdint>
#include <cstddef>

#define HIDDEN 768
#define HEADS 12
#define HD 64
#define SEQ 4096
#define NSPLIT 4

typedef __hip_bfloat16 bf16;
typedef short bf16x8 __attribute__((ext_vector_type(8)));
typedef float f32x4 __attribute__((ext_vector_type(4)));

// 0.125 (1/sqrt(64)) * log2(e): folded into Q so softmax runs in exp2 domain
#define QSCALE 0.18033688011112042f

static __device__ __forceinline__ void gload_lds16(const bf16* g, bf16* l) {
  __builtin_amdgcn_global_load_lds(
      (const __attribute__((address_space(1))) unsigned int*)(g),
      (__attribute__((address_space(3))) unsigned int*)(l), 16, 0, 0);
}

static __device__ __forceinline__ unsigned cvt_pk_bf16(float lo, float hi) {
  unsigned r;
  asm("v_cvt_pk_bf16_f32 %0, %1, %2" : "=v"(r) : "v"(lo), "v"(hi));
  return r;
}

// ---------------- fused prep: x->bf16 + all weight transposes ----------------
// grid: [0,3072) cvt_x; [3072,3504) Wq/Wk/Wv tiles; [3504,3648) Wo tiles.
__global__ __launch_bounds__(256) void prep_kernel(
    const float* __restrict__ x, const float* __restrict__ Wq,
    const float* __restrict__ Wk, const float* __restrict__ Wv,
    const float* __restrict__ Wo, bf16* __restrict__ xb,
    bf16* __restrict__ Wt, bf16* __restrict__ Wot) {
  __shared__ float t[64][65];
  int i = blockIdx.x;
  if (i < 3072) {
    int idx = i * 256 + threadIdx.x;
    float4 v = ((const float4*)x)[idx];
    union { bf16 h[4]; short4 s4; } u;
    u.h[0] = __float2bfloat16(v.x);
    u.h[1] = __float2bfloat16(v.y);
    u.h[2] = __float2bfloat16(v.z);
    u.h[3] = __float2bfloat16(v.w);
    ((short4*)xb)[idx] = u.s4;
    return;
  }
  i -= 3072;
  const float* src;
  bf16* dst;
  int R, C, tr, tc;
  if (i < 432) {                     // Wq/Wk/Wv: per-head [768][64] -> [64][768]
    int m = i / 144;
    int j = i - m * 144;
    int b = j / 12;
    tr = j - b * 12; tc = 0;
    src = (m == 0 ? Wq : m == 1 ? Wk : Wv) + (size_t)b * 768 * 64;
    dst = Wt + (size_t)m * 589824 + (size_t)b * 768 * 64;
    R = 768; C = 64;
  } else {                           // Wo: [768][768] -> [768][768]^T
    int j = i - 432;
    tr = j / 12; tc = j - tr * 12;
    src = Wo; dst = Wot; R = 768; C = 768;
  }
  int r0 = tr << 6, c0 = tc << 6;
#pragma unroll
  for (int k = threadIdx.x; k < 4096; k += 256) {
    int r = k >> 6, c = k & 63;
    t[r][c] = src[(size_t)(r0 + r) * C + c0 + c];
  }
  __syncthreads();
#pragma unroll
  for (int k = threadIdx.x; k < 4096; k += 256) {
    int c = k >> 6, r = k & 63;
    dst[(size_t)(c0 + c) * R + r0 + r] = __float2bfloat16(t[r][c]);
  }
}

// ---------------- GEMM: C[M][N] = A[M][K] * Bt[N][K]^T ----------------
template <int EPI>
__global__ __launch_bounds__(256) void gemm_kernel(
    const bf16* __restrict__ A, const bf16* __restrict__ Bt,
    int M, int N, int K, int ntn,
    const float* __restrict__ bq, const float* __restrict__ bk,
    const float* __restrict__ bv,
    bf16* __restrict__ Qb, bf16* __restrict__ Kb, bf16* __restrict__ Vt,
    const float* __restrict__ bo, float* __restrict__ outp) {
  __shared__ bf16 sA[2][128 * 32];
  __shared__ bf16 sB[2][128 * 32];
  __shared__ bf16 strans[4][16][20];

  int bid = blockIdx.x;
  int bm = bid / ntn, bn = bid - bm * ntn;
  int tid = threadIdx.x;
  int w = tid >> 6, l = tid & 63;
  int wr = w >> 1, wc = w & 1;
  int l15 = l & 15, g = l >> 4;

  const bf16* Ab = A + (size_t)bm * 128 * K;
  const bf16* Bb = Bt + (size_t)bn * 128 * K;

  int sr = tid >> 2;              // staging row 0..63
  int sc = (tid & 3) << 3;        // staging col (elems)

  f32x4 acc[4][4] = {};
  int NT = K >> 5;
  int cur = 0;

  auto stage = [&](int buf, int kt) {
    const bf16* ga = Ab + (size_t)sr * K + kt * 32 + sc;
    const bf16* gb = Bb + (size_t)sr * K + kt * 32 + sc;
    bf16* la = &sA[buf][w << 9];
    bf16* lb = &sB[buf][w << 9];
    gload_lds16(ga, la);
    gload_lds16(ga + (size_t)64 * K, la + 2048);
    gload_lds16(gb, lb);
    gload_lds16(gb + (size_t)64 * K, lb + 2048);
  };

  stage(0, 0);
  for (int kt = 0; kt < NT; ++kt) {
    __syncthreads();
    if (kt + 1 < NT) stage(cur ^ 1, kt + 1);
    const bf16* pa = &sA[cur][0];
    const bf16* pb = &sB[cur][0];
    bf16x8 af[4], bfr[4];
#pragma unroll
    for (int m = 0; m < 4; ++m)
      af[m] = *(const bf16x8*)&pa[(wr * 64 + m * 16 + l15) * 32 + g * 8];
#pragma unroll
    for (int n = 0; n < 4; ++n)
      bfr[n] = *(const bf16x8*)&pb[(wc * 64 + n * 16 + l15) * 32 + g * 8];
#pragma unroll
    for (int m = 0; m < 4; ++m)
#pragma unroll
      for (int n = 0; n < 4; ++n)
        acc[m][n] = __builtin_amdgcn_mfma_f32_16x16x32_bf16(af[m], bfr[n], acc[m][n], 0, 0, 0);
    cur ^= 1;
  }

  if (EPI == 0) {
#pragma unroll
    for (int n = 0; n < 4; ++n) {
      int j = bn * 128 + wc * 64 + n * 16 + l15;
      int mat = j / 768;
      int jj = j - mat * 768;
      int h = jj >> 6, e = jj & 63;
      const float* bias = (mat == 0) ? bq : (mat == 1) ? bk : bv;
      float bb = bias[h * 64 + e];
      float scl = (mat == 0) ? QSCALE : 1.0f;   // Q pre-scaled into exp2 domain
#pragma unroll
      for (int m = 0; m < 4; ++m) {
        int s0m = bm * 128 + wr * 64 + m * 16;
        if (mat < 2) {
          bf16* dst = (mat == 0 ? Qb : Kb) + (size_t)h * SEQ * 64;
#pragma unroll
          for (int r = 0; r < 4; ++r)
            dst[(size_t)(s0m + g * 4 + r) * 64 + e] = __float2bfloat16((acc[m][n][r] + bb) * scl);
        } else {
#pragma unroll
          for (int r = 0; r < 4; ++r)
            strans[w][g * 4 + r][l15] = __float2bfloat16(acc[m][n][r] + bb);
          int e0f = e - l15;
          bf16* dst = Vt + (size_t)h * SEQ * 64;
#pragma unroll
          for (int r = 0; r < 4; ++r) {
            bf16 val = strans[w][l15][g * 4 + r];
            dst[(size_t)(e0f + g * 4 + r) * SEQ + s0m + l15] = val;
          }
        }
      }
    }
  } else {
#pragma unroll
    for (int n = 0; n < 4; ++n) {
      int j = bn * 128 + wc * 64 + n * 16 + l15;
      float bb = bo[j];
#pragma unroll
      for (int m = 0; m < 4; ++m) {
        int s0m = bm * 128 + wr * 64 + m * 16;
#pragma unroll
        for (int r = 0; r < 4; ++r)
          outp[(size_t)(s0m + g * 4 + r) * HIDDEN + j] = acc[m][n][r] + bb;
      }
    }
  }
}

// ---------------- flash attention v7: split-KV x4, 8-wave blocks ----------------
// grid (SEQ/128, HEADS, NSPLIT) = 1536 blocks x 8 waves -> 4 blocks/CU resident
// (32-wave slot cap; LDS 4x32KB=128KB fits). Proven v5 2-buffer inner loop.
__global__ __launch_bounds__(512) void flash_kernel(
    const bf16* __restrict__ Qb, const bf16* __restrict__ Kb,
    const bf16* __restrict__ Vt, float* __restrict__ partC,
    float* __restrict__ partM, float* __restrict__ partL) {
  __shared__ bf16 sK[2][64 * 64];   // [t][e], 128B rows, swizzled
  __shared__ bf16 sV[2][64 * 64];   // [e][t], 128B rows, swizzled

  const int head = blockIdx.y;
  const int split = blockIdx.z;
  const int w = threadIdx.x >> 6, l = threadIdx.x & 63;
  const int l15 = l & 15, g = l >> 4;
  const int sw = l15 & 7;
  const int q0w = blockIdx.x * 128 + w * 16;

  const bf16* Qh = Qb + (size_t)head * SEQ * 64;
  const bf16* Kh = Kb + (size_t)head * SEQ * 64;
  const bf16* Vh = Vt + (size_t)head * SEQ * 64;   // [64][SEQ]

  // Q as B-operand: lane holds Q[col=q0w+l15][k-slice g]
  bf16x8 aq[2];
  aq[0] = *(const bf16x8*)&Qh[(size_t)(q0w + l15) * 64 + g * 8];
  aq[1] = *(const bf16x8*)&Qh[(size_t)(q0w + l15) * 64 + 32 + g * 8];

  float mrun = -1e30f, lsum = 0.f;   // scalar per lane (its q-row = l15)
  f32x4 cacc[4] = {};

  const int lr8 = l >> 3;            // row-in-call 0..7
  const int csrc = (l & 7) ^ lr8;    // pre-swizzled source chunk

  // wave w stages K rows [w*8, w*8+8) and V rows [w*8, w*8+8)
  auto stage = [&](int buf, int kt) {
    int t0 = kt * 64;
    const bf16* gk = Kh + (size_t)(t0 + w * 8 + lr8) * 64 + csrc * 8;
    gload_lds16(gk, &sK[buf][(w * 8) * 64]);
    const bf16* gv = Vh + (size_t)(w * 8 + lr8) * SEQ + t0 + csrc * 8;
    gload_lds16(gv, &sV[buf][(w * 8) * 64]);
  };

  const int kt0 = split * (SEQ / 64 / NSPLIT);
  const int kt1 = kt0 + SEQ / 64 / NSPLIT;
  stage(0, kt0);
  int cur = 0;
  const bool ge = (l & 16) == 0;     // g even

  for (int kt = kt0; kt < kt1; ++kt) {
    __syncthreads();               // drains prev stage (vmcnt) + protects buffers
    if (kt + 1 < kt1) stage(cur ^ 1, kt + 1);
    const bf16* kb = &sK[cur][0];
    const bf16* vb = &sV[cur][0];

    // ---- S^T = K·Q^T: lane holds S[t=n*16+g*4+r][q=l15] ----
    f32x4 sc8[4] = {};
    __builtin_amdgcn_s_setprio(1);
#pragma unroll
    for (int n = 0; n < 4; ++n) {
      bf16x8 b0 = *(const bf16x8*)&kb[(n * 16 + l15) * 64 + (g ^ sw) * 8];
      bf16x8 b1 = *(const bf16x8*)&kb[(n * 16 + l15) * 64 + ((4 + g) ^ sw) * 8];
      sc8[n] = __builtin_amdgcn_mfma_f32_16x16x32_bf16(b0, aq[0], sc8[n], 0, 0, 0);
      sc8[n] = __builtin_amdgcn_mfma_f32_16x16x32_bf16(b1, aq[1], sc8[n], 0, 0, 0);
    }
    __builtin_amdgcn_s_setprio(0);

    // ---- row-max: 15 local fmax + 2 cross-g shuffles ----
    float vm = fmaxf(fmaxf(fmaxf(sc8[0][0], sc8[0][1]), fmaxf(sc8[0][2], sc8[0][3])),
                     fmaxf(fmaxf(sc8[1][0], sc8[1][1]), fmaxf(sc8[1][2], sc8[1][3])));
    vm = fmaxf(vm, fmaxf(fmaxf(fmaxf(sc8[2][0], sc8[2][1]), fmaxf(sc8[2][2], sc8[2][3])),
                         fmaxf(fmaxf(sc8[3][0], sc8[3][1]), fmaxf(sc8[3][2], sc8[3][3]))));
    vm = fmaxf(vm, __shfl_xor(vm, 16));
    vm = fmaxf(vm, __shfl_xor(vm, 32));

    // ---- defer-rescale (THR=8 in log2 domain) ----
    if (__any(vm > mrun + 8.0f)) {
      float mn = fmaxf(mrun, vm);
      float a = __builtin_amdgcn_exp2f(mrun - mn);
      mrun = mn;
      lsum *= a;
      float aqr[4];
#pragma unroll
      for (int r = 0; r < 4; ++r) aqr[r] = __shfl(a, g * 4 + r);
#pragma unroll
      for (int f = 0; f < 4; ++f)
#pragma unroll
        for (int r = 0; r < 4; ++r) cacc[f][r] *= aqr[r];
    }

    // ---- P = exp2(S - m), packed in-register ----
    unsigned X[4][2];
    float ls0 = 0.f, ls1 = 0.f;
#pragma unroll
    for (int n = 0; n < 4; ++n) {
#pragma unroll
      for (int h = 0; h < 2; ++h) {
        float p0 = __builtin_amdgcn_exp2f(sc8[n][2 * h] - mrun);
        float p1 = __builtin_amdgcn_exp2f(sc8[n][2 * h + 1] - mrun);
        ls0 += p0; ls1 += p1;
        X[n][h] = cvt_pk_bf16(p0, p1);
      }
    }
    lsum += ls0 + ls1;

    // ---- route packed P into PV A-frags + PV ----
#pragma unroll
    for (int kkl = 0; kkl < 2; ++kkl) {
      unsigned P0 = X[2 * kkl][0], Q0 = X[2 * kkl + 1][0];
      unsigned P1 = X[2 * kkl][1], Q1 = X[2 * kkl + 1][1];
      asm("v_permlane32_swap_b32 %0, %1" : "+v"(P0), "+v"(Q0));
      asm("v_permlane32_swap_b32 %0, %1" : "+v"(P1), "+v"(Q1));
      unsigned sP0 = __shfl_xor((int)P0, 16);
      unsigned sQ0 = __shfl_xor((int)Q0, 16);
      unsigned sP1 = __shfl_xor((int)P1, 16);
      unsigned sQ1 = __shfl_xor((int)Q1, 16);
      union { unsigned u[4]; bf16x8 v8; } ap;
      ap.u[0] = ge ? P0 : sQ0;
      ap.u[1] = ge ? P1 : sQ1;
      ap.u[2] = ge ? sP0 : Q0;
      ap.u[3] = ge ? sP1 : Q1;
      __builtin_amdgcn_s_setprio(1);
#pragma unroll
      for (int f = 0; f < 4; ++f) {
        bf16x8 bv8 = *(const bf16x8*)&vb[(f * 16 + l15) * 64 + ((kkl * 4 + g) ^ sw) * 8];
        cacc[f] = __builtin_amdgcn_mfma_f32_16x16x32_bf16(ap.v8, bv8, cacc[f], 0, 0, 0);
      }
      __builtin_amdgcn_s_setprio(0);
    }
    cur ^= 1;
  }

  // ---- epilogue: reduce l across g, write unnormalized partials ----
  float s = lsum;
  s += __shfl_xor(s, 16);
  s += __shfl_xor(s, 32);

  float* pcw = partC + (size_t)split * SEQ * HIDDEN;
#pragma unroll
  for (int f = 0; f < 4; ++f)
#pragma unroll
    for (int r = 0; r < 4; ++r)
      pcw[(size_t)(q0w + g * 4 + r) * HIDDEN + head * 64 + f * 16 + l15] = cacc[f][r];
  if (l < 16) {
    size_t mi = (size_t)split * HEADS * SEQ + (size_t)head * SEQ + q0w + l15;
    partM[mi] = mrun;
    partL[mi] = s;
  }
}

// ---------------- split-KV combine (NSPLIT-way exact merge) ----------------
__global__ __launch_bounds__(256) void combine_kernel(
    const float* __restrict__ partC, const float* __restrict__ partM,
    const float* __restrict__ partL, bf16* __restrict__ ctx) {
  int i = blockIdx.x * 256 + threadIdx.x;   // one float4 (4 elems) per thread
  int idx = i * 4;
  int s = idx / HIDDEN, c = idx - s * HIDDEN;
  int h = c >> 6;
  size_t mi = (size_t)h * SEQ + s;
  float m[NSPLIT], lv[NSPLIT];
  float ms = -1e30f;
#pragma unroll
  for (int sp = 0; sp < NSPLIT; ++sp) {
    m[sp] = partM[(size_t)sp * HEADS * SEQ + mi];
    lv[sp] = partL[(size_t)sp * HEADS * SEQ + mi];
    ms = fmaxf(ms, m[sp]);
  }
  float wgt[NSPLIT];
  float denom = 0.f;
#pragma unroll
  for (int sp = 0; sp < NSPLIT; ++sp) {
    wgt[sp] = __builtin_amdgcn_exp2f(m[sp] - ms);
    denom += lv[sp] * wgt[sp];
  }
  float inv = 1.0f / denom;
  float ax = 0.f, ay = 0.f, az = 0.f, aw = 0.f;
#pragma unroll
  for (int sp = 0; sp < NSPLIT; ++sp) {
    float4 c4 = ((const float4*)(partC + (size_t)sp * SEQ * HIDDEN))[i];
    ax += c4.x * wgt[sp];
    ay += c4.y * wgt[sp];
    az += c4.z * wgt[sp];
    aw += c4.w * wgt[sp];
  }
  union { bf16 h4[4]; short4 s4; } u;
  u.h4[0] = __float2bfloat16(ax * inv);
  u.h4[1] = __float2bfloat16(ay * inv);
  u.h4[2] = __float2bfloat16(az * inv);
  u.h4[3] = __float2bfloat16(aw * inv);
  ((short4*)ctx)[i] = u.s4;
}

// ---------------- launcher ----------------
extern "C" void kernel_launch(void* const* d_in, const int* in_sizes, int n_in,
                              void* d_out, int out_size, void* d_ws, size_t ws_size,
                              hipStream_t stream) {
  const float* x = (const float*)d_in[0];
  const float* Wq = (const float*)d_in[1];
  const float* Wk = (const float*)d_in[2];
  const float* Wv = (const float*)d_in[3];
  const float* bq = (const float*)d_in[4];
  const float* bk = (const float*)d_in[5];
  const float* bv = (const float*)d_in[6];
  const float* Wo = (const float*)d_in[7];
  const float* bo = (const float*)d_in[8];
  float* outp = (float*)d_out;

  char* ws = (char*)d_ws;
  bf16* xb = (bf16*)ws;   ws += (size_t)SEQ * HIDDEN * 2;
  bf16* Wt = (bf16*)ws;   ws += (size_t)3 * HIDDEN * HIDDEN * 2;
  bf16* Wot = (bf16*)ws;  ws += (size_t)HIDDEN * HIDDEN * 2;
  bf16* Qb = (bf16*)ws;   ws += (size_t)SEQ * HIDDEN * 2;
  bf16* Kb = (bf16*)ws;   ws += (size_t)SEQ * HIDDEN * 2;
  bf16* Vt = (bf16*)ws;   ws += (size_t)SEQ * HIDDEN * 2;
  bf16* ctx = (bf16*)ws;  ws += (size_t)SEQ * HIDDEN * 2;
  float* partC = (float*)ws; ws += (size_t)NSPLIT * SEQ * HIDDEN * 4;
  float* partM = (float*)ws; ws += (size_t)NSPLIT * HEADS * SEQ * 4;
  float* partL = (float*)ws; ws += (size_t)NSPLIT * HEADS * SEQ * 4;

  prep_kernel<<<3648, 256, 0, stream>>>(x, Wq, Wk, Wv, Wo, xb, Wt, Wot);

  gemm_kernel<0><<<32 * 18, 256, 0, stream>>>(xb, Wt, SEQ, 2304, 768, 18,
                                              bq, bk, bv, Qb, Kb, Vt, nullptr, nullptr);

  flash_kernel<<<dim3(SEQ / 128, HEADS, NSPLIT), 512, 0, stream>>>(Qb, Kb, Vt,
                                                                   partC, partM, partL);
  combine_kernel<<<SEQ * HIDDEN / 4 / 256, 256, 0, stream>>>(partC, partM, partL, ctx);

  gemm_kernel<1><<<32 * 6, 256, 0, stream>>>(ctx, Wot, SEQ, 768, 768, 6,
                                             nullptr, nullptr, nullptr, nullptr, nullptr,
                                             nullptr, bo, outp);
}

// Round 9
// 150.499 us; speedup vs baseline: 2.8551x; 1.0020x over previous
//
#include <hip/hip_runtime.h>
#include <hip/hip_bf16.h>
#include <cstdint>
#include <cstddef>

#define HIDDEN 768
#define HEADS 12
#define HD 64
#define SEQ 4096
#define NSPLIT 8

typedef __hip_bfloat16 bf16;
typedef short bf16x8 __attribute__((ext_vector_type(8)));
typedef float f32x4 __attribute__((ext_vector_type(4)));

// 0.125 (1/sqrt(64)) * log2(e): folded into Q so softmax runs in exp2 domain
#define QSCALE 0.18033688011112042f

static __device__ __forceinline__ void gload_lds16(const bf16* g, bf16* l) {
  __builtin_amdgcn_global_load_lds(
      (const __attribute__((address_space(1))) unsigned int*)(g),
      (__attribute__((address_space(3))) unsigned int*)(l), 16, 0, 0);
}

static __device__ __forceinline__ unsigned cvt_pk_bf16(float lo, float hi) {
  unsigned r;
  asm("v_cvt_pk_bf16_f32 %0, %1, %2" : "=v"(r) : "v"(lo), "v"(hi));
  return r;
}

static __device__ __forceinline__ float b2f(short s) {
  union { unsigned u; float f; } v;
  v.u = ((unsigned)(unsigned short)s) << 16;
  return v.f;
}

// ---------------- fused prep: x->bf16 + all weight transposes ----------------
// grid: [0,3072) cvt_x; [3072,3504) Wq/Wk/Wv tiles; [3504,3648) Wo tiles.
__global__ __launch_bounds__(256) void prep_kernel(
    const float* __restrict__ x, const float* __restrict__ Wq,
    const float* __restrict__ Wk, const float* __restrict__ Wv,
    const float* __restrict__ Wo, bf16* __restrict__ xb,
    bf16* __restrict__ Wt, bf16* __restrict__ Wot) {
  __shared__ float t[64][65];
  int i = blockIdx.x;
  if (i < 3072) {
    int idx = i * 256 + threadIdx.x;
    float4 v = ((const float4*)x)[idx];
    union { bf16 h[4]; short4 s4; } u;
    u.h[0] = __float2bfloat16(v.x);
    u.h[1] = __float2bfloat16(v.y);
    u.h[2] = __float2bfloat16(v.z);
    u.h[3] = __float2bfloat16(v.w);
    ((short4*)xb)[idx] = u.s4;
    return;
  }
  i -= 3072;
  const float* src;
  bf16* dst;
  int R, C, tr, tc;
  if (i < 432) {                     // Wq/Wk/Wv: per-head [768][64] -> [64][768]
    int m = i / 144;
    int j = i - m * 144;
    int b = j / 12;
    tr = j - b * 12; tc = 0;
    src = (m == 0 ? Wq : m == 1 ? Wk : Wv) + (size_t)b * 768 * 64;
    dst = Wt + (size_t)m * 589824 + (size_t)b * 768 * 64;
    R = 768; C = 64;
  } else {                           // Wo: [768][768] -> [768][768]^T
    int j = i - 432;
    tr = j / 12; tc = j - tr * 12;
    src = Wo; dst = Wot; R = 768; C = 768;
  }
  int r0 = tr << 6, c0 = tc << 6;
#pragma unroll
  for (int k = threadIdx.x; k < 4096; k += 256) {
    int r = k >> 6, c = k & 63;
    t[r][c] = src[(size_t)(r0 + r) * C + c0 + c];
  }
  __syncthreads();
#pragma unroll
  for (int k = threadIdx.x; k < 4096; k += 256) {
    int c = k >> 6, r = k & 63;
    dst[(size_t)(c0 + c) * R + r0 + r] = __float2bfloat16(t[r][c]);
  }
}

// ---------------- GEMM: C[M][N] = A[M][K] * Bt[N][K]^T ----------------
template <int EPI>
__global__ __launch_bounds__(256) void gemm_kernel(
    const bf16* __restrict__ A, const bf16* __restrict__ Bt,
    int M, int N, int K, int ntn,
    const float* __restrict__ bq, const float* __restrict__ bk,
    const float* __restrict__ bv,
    bf16* __restrict__ Qb, bf16* __restrict__ Kb, bf16* __restrict__ Vt,
    const float* __restrict__ bo, float* __restrict__ outp) {
  __shared__ bf16 sA[2][128 * 32];
  __shared__ bf16 sB[2][128 * 32];
  __shared__ bf16 strans[4][16][20];

  int bid = blockIdx.x;
  int bm = bid / ntn, bn = bid - bm * ntn;
  int tid = threadIdx.x;
  int w = tid >> 6, l = tid & 63;
  int wr = w >> 1, wc = w & 1;
  int l15 = l & 15, g = l >> 4;

  const bf16* Ab = A + (size_t)bm * 128 * K;
  const bf16* Bb = Bt + (size_t)bn * 128 * K;

  int sr = tid >> 2;              // staging row 0..63
  int sc = (tid & 3) << 3;        // staging col (elems)

  f32x4 acc[4][4] = {};
  int NT = K >> 5;
  int cur = 0;

  auto stage = [&](int buf, int kt) {
    const bf16* ga = Ab + (size_t)sr * K + kt * 32 + sc;
    const bf16* gb = Bb + (size_t)sr * K + kt * 32 + sc;
    bf16* la = &sA[buf][w << 9];
    bf16* lb = &sB[buf][w << 9];
    gload_lds16(ga, la);
    gload_lds16(ga + (size_t)64 * K, la + 2048);
    gload_lds16(gb, lb);
    gload_lds16(gb + (size_t)64 * K, lb + 2048);
  };

  stage(0, 0);
  for (int kt = 0; kt < NT; ++kt) {
    __syncthreads();
    if (kt + 1 < NT) stage(cur ^ 1, kt + 1);
    const bf16* pa = &sA[cur][0];
    const bf16* pb = &sB[cur][0];
    bf16x8 af[4], bfr[4];
#pragma unroll
    for (int m = 0; m < 4; ++m)
      af[m] = *(const bf16x8*)&pa[(wr * 64 + m * 16 + l15) * 32 + g * 8];
#pragma unroll
    for (int n = 0; n < 4; ++n)
      bfr[n] = *(const bf16x8*)&pb[(wc * 64 + n * 16 + l15) * 32 + g * 8];
#pragma unroll
    for (int m = 0; m < 4; ++m)
#pragma unroll
      for (int n = 0; n < 4; ++n)
        acc[m][n] = __builtin_amdgcn_mfma_f32_16x16x32_bf16(af[m], bfr[n], acc[m][n], 0, 0, 0);
    cur ^= 1;
  }

  if (EPI == 0) {
#pragma unroll
    for (int n = 0; n < 4; ++n) {
      int j = bn * 128 + wc * 64 + n * 16 + l15;
      int mat = j / 768;
      int jj = j - mat * 768;
      int h = jj >> 6, e = jj & 63;
      const float* bias = (mat == 0) ? bq : (mat == 1) ? bk : bv;
      float bb = bias[h * 64 + e];
      float scl = (mat == 0) ? QSCALE : 1.0f;   // Q pre-scaled into exp2 domain
#pragma unroll
      for (int m = 0; m < 4; ++m) {
        int s0m = bm * 128 + wr * 64 + m * 16;
        if (mat < 2) {
          bf16* dst = (mat == 0 ? Qb : Kb) + (size_t)h * SEQ * 64;
#pragma unroll
          for (int r = 0; r < 4; ++r)
            dst[(size_t)(s0m + g * 4 + r) * 64 + e] = __float2bfloat16((acc[m][n][r] + bb) * scl);
        } else {
#pragma unroll
          for (int r = 0; r < 4; ++r)
            strans[w][g * 4 + r][l15] = __float2bfloat16(acc[m][n][r] + bb);
          int e0f = e - l15;
          bf16* dst = Vt + (size_t)h * SEQ * 64;
#pragma unroll
          for (int r = 0; r < 4; ++r) {
            bf16 val = strans[w][l15][g * 4 + r];
            dst[(size_t)(e0f + g * 4 + r) * SEQ + s0m + l15] = val;
          }
        }
      }
    }
  } else {
#pragma unroll
    for (int n = 0; n < 4; ++n) {
      int j = bn * 128 + wc * 64 + n * 16 + l15;
      float bb = bo[j];
#pragma unroll
      for (int m = 0; m < 4; ++m) {
        int s0m = bm * 128 + wr * 64 + m * 16;
#pragma unroll
        for (int r = 0; r < 4; ++r)
          outp[(size_t)(s0m + g * 4 + r) * HIDDEN + j] = acc[m][n][r] + bb;
      }
    }
  }
}

// ---------------- flash attention v8: split-KV x8 (integral rounds) ----------
// grid (SEQ/128, HEADS, NSPLIT) = 3072 blocks = 12 blocks/CU work, 4 resident
// (32-wave cap) -> exactly 3 full rounds, no partial-occupancy tail.
// Partials stored bf16 (halves partC traffic vs f32).
__global__ __launch_bounds__(512) void flash_kernel(
    const bf16* __restrict__ Qb, const bf16* __restrict__ Kb,
    const bf16* __restrict__ Vt, bf16* __restrict__ partC,
    float* __restrict__ partM, float* __restrict__ partL) {
  __shared__ bf16 sK[2][64 * 64];   // [t][e], 128B rows, swizzled
  __shared__ bf16 sV[2][64 * 64];   // [e][t], 128B rows, swizzled

  const int head = blockIdx.y;
  const int split = blockIdx.z;
  const int w = threadIdx.x >> 6, l = threadIdx.x & 63;
  const int l15 = l & 15, g = l >> 4;
  const int sw = l15 & 7;
  const int q0w = blockIdx.x * 128 + w * 16;

  const bf16* Qh = Qb + (size_t)head * SEQ * 64;
  const bf16* Kh = Kb + (size_t)head * SEQ * 64;
  const bf16* Vh = Vt + (size_t)head * SEQ * 64;   // [64][SEQ]

  // Q as B-operand: lane holds Q[col=q0w+l15][k-slice g]
  bf16x8 aq[2];
  aq[0] = *(const bf16x8*)&Qh[(size_t)(q0w + l15) * 64 + g * 8];
  aq[1] = *(const bf16x8*)&Qh[(size_t)(q0w + l15) * 64 + 32 + g * 8];

  float mrun = -1e30f, lsum = 0.f;   // scalar per lane (its q-row = l15)
  f32x4 cacc[4] = {};

  const int lr8 = l >> 3;            // row-in-call 0..7
  const int csrc = (l & 7) ^ lr8;    // pre-swizzled source chunk

  // wave w stages K rows [w*8, w*8+8) and V rows [w*8, w*8+8)
  auto stage = [&](int buf, int kt) {
    int t0 = kt * 64;
    const bf16* gk = Kh + (size_t)(t0 + w * 8 + lr8) * 64 + csrc * 8;
    gload_lds16(gk, &sK[buf][(w * 8) * 64]);
    const bf16* gv = Vh + (size_t)(w * 8 + lr8) * SEQ + t0 + csrc * 8;
    gload_lds16(gv, &sV[buf][(w * 8) * 64]);
  };

  const int kt0 = split * (SEQ / 64 / NSPLIT);
  const int kt1 = kt0 + SEQ / 64 / NSPLIT;
  stage(0, kt0);
  int cur = 0;
  const bool ge = (l & 16) == 0;     // g even

  for (int kt = kt0; kt < kt1; ++kt) {
    __syncthreads();               // drains prev stage (vmcnt) + protects buffers
    if (kt + 1 < kt1) stage(cur ^ 1, kt + 1);
    const bf16* kb = &sK[cur][0];
    const bf16* vb = &sV[cur][0];

    // ---- S^T = K·Q^T: lane holds S[t=n*16+g*4+r][q=l15] ----
    f32x4 sc8[4] = {};
    __builtin_amdgcn_s_setprio(1);
#pragma unroll
    for (int n = 0; n < 4; ++n) {
      bf16x8 b0 = *(const bf16x8*)&kb[(n * 16 + l15) * 64 + (g ^ sw) * 8];
      bf16x8 b1 = *(const bf16x8*)&kb[(n * 16 + l15) * 64 + ((4 + g) ^ sw) * 8];
      sc8[n] = __builtin_amdgcn_mfma_f32_16x16x32_bf16(b0, aq[0], sc8[n], 0, 0, 0);
      sc8[n] = __builtin_amdgcn_mfma_f32_16x16x32_bf16(b1, aq[1], sc8[n], 0, 0, 0);
    }
    __builtin_amdgcn_s_setprio(0);

    // ---- row-max: 15 local fmax + 2 cross-g shuffles ----
    float vm = fmaxf(fmaxf(fmaxf(sc8[0][0], sc8[0][1]), fmaxf(sc8[0][2], sc8[0][3])),
                     fmaxf(fmaxf(sc8[1][0], sc8[1][1]), fmaxf(sc8[1][2], sc8[1][3])));
    vm = fmaxf(vm, fmaxf(fmaxf(fmaxf(sc8[2][0], sc8[2][1]), fmaxf(sc8[2][2], sc8[2][3])),
                         fmaxf(fmaxf(sc8[3][0], sc8[3][1]), fmaxf(sc8[3][2], sc8[3][3]))));
    vm = fmaxf(vm, __shfl_xor(vm, 16));
    vm = fmaxf(vm, __shfl_xor(vm, 32));

    // ---- defer-rescale (THR=8 in log2 domain) ----
    if (__any(vm > mrun + 8.0f)) {
      float mn = fmaxf(mrun, vm);
      float a = __builtin_amdgcn_exp2f(mrun - mn);
      mrun = mn;
      lsum *= a;
      float aqr[4];
#pragma unroll
      for (int r = 0; r < 4; ++r) aqr[r] = __shfl(a, g * 4 + r);
#pragma unroll
      for (int f = 0; f < 4; ++f)
#pragma unroll
        for (int r = 0; r < 4; ++r) cacc[f][r] *= aqr[r];
    }

    // ---- P = exp2(S - m), packed in-register ----
    unsigned X[4][2];
    float ls0 = 0.f, ls1 = 0.f;
#pragma unroll
    for (int n = 0; n < 4; ++n) {
#pragma unroll
      for (int h = 0; h < 2; ++h) {
        float p0 = __builtin_amdgcn_exp2f(sc8[n][2 * h] - mrun);
        float p1 = __builtin_amdgcn_exp2f(sc8[n][2 * h + 1] - mrun);
        ls0 += p0; ls1 += p1;
        X[n][h] = cvt_pk_bf16(p0, p1);
      }
    }
    lsum += ls0 + ls1;

    // ---- route packed P into PV A-frags + PV ----
#pragma unroll
    for (int kkl = 0; kkl < 2; ++kkl) {
      unsigned P0 = X[2 * kkl][0], Q0 = X[2 * kkl + 1][0];
      unsigned P1 = X[2 * kkl][1], Q1 = X[2 * kkl + 1][1];
      asm("v_permlane32_swap_b32 %0, %1" : "+v"(P0), "+v"(Q0));
      asm("v_permlane32_swap_b32 %0, %1" : "+v"(P1), "+v"(Q1));
      unsigned sP0 = __shfl_xor((int)P0, 16);
      unsigned sQ0 = __shfl_xor((int)Q0, 16);
      unsigned sP1 = __shfl_xor((int)P1, 16);
      unsigned sQ1 = __shfl_xor((int)Q1, 16);
      union { unsigned u[4]; bf16x8 v8; } ap;
      ap.u[0] = ge ? P0 : sQ0;
      ap.u[1] = ge ? P1 : sQ1;
      ap.u[2] = ge ? sP0 : Q0;
      ap.u[3] = ge ? sP1 : Q1;
      __builtin_amdgcn_s_setprio(1);
#pragma unroll
      for (int f = 0; f < 4; ++f) {
        bf16x8 bv8 = *(const bf16x8*)&vb[(f * 16 + l15) * 64 + ((kkl * 4 + g) ^ sw) * 8];
        cacc[f] = __builtin_amdgcn_mfma_f32_16x16x32_bf16(ap.v8, bv8, cacc[f], 0, 0, 0);
      }
      __builtin_amdgcn_s_setprio(0);
    }
    cur ^= 1;
  }

  // ---- epilogue: reduce l across g, write unnormalized bf16 partials ----
  float s = lsum;
  s += __shfl_xor(s, 16);
  s += __shfl_xor(s, 32);

  bf16* pcw = partC + (size_t)split * SEQ * HIDDEN;
#pragma unroll
  for (int f = 0; f < 4; ++f)
#pragma unroll
    for (int r = 0; r < 4; ++r)
      pcw[(size_t)(q0w + g * 4 + r) * HIDDEN + head * 64 + f * 16 + l15] =
          __float2bfloat16(cacc[f][r]);
  if (l < 16) {
    size_t mi = (size_t)split * HEADS * SEQ + (size_t)head * SEQ + q0w + l15;
    partM[mi] = mrun;
    partL[mi] = s;
  }
}

// ---------------- split-KV combine (NSPLIT-way exact merge, bf16 partials) ----
__global__ __launch_bounds__(256) void combine_kernel(
    const bf16* __restrict__ partC, const float* __restrict__ partM,
    const float* __restrict__ partL, bf16* __restrict__ ctx) {
  int i = blockIdx.x * 256 + threadIdx.x;   // 4 elems per thread
  int idx = i * 4;
  int s = idx / HIDDEN, c = idx - s * HIDDEN;
  int h = c >> 6;
  size_t mi = (size_t)h * SEQ + s;
  float m[NSPLIT], lv[NSPLIT];
  float ms = -1e30f;
#pragma unroll
  for (int sp = 0; sp < NSPLIT; ++sp) {
    m[sp] = partM[(size_t)sp * HEADS * SEQ + mi];
    lv[sp] = partL[(size_t)sp * HEADS * SEQ + mi];
    ms = fmaxf(ms, m[sp]);
  }
  float wgt[NSPLIT];
  float denom = 0.f;
#pragma unroll
  for (int sp = 0; sp < NSPLIT; ++sp) {
    wgt[sp] = __builtin_amdgcn_exp2f(m[sp] - ms);
    denom += lv[sp] * wgt[sp];
  }
  float inv = 1.0f / denom;
  float ax = 0.f, ay = 0.f, az = 0.f, aw = 0.f;
#pragma unroll
  for (int sp = 0; sp < NSPLIT; ++sp) {
    short4 c4 = ((const short4*)(partC + (size_t)sp * SEQ * HIDDEN))[i];
    ax += b2f(c4.x) * wgt[sp];
    ay += b2f(c4.y) * wgt[sp];
    az += b2f(c4.z) * wgt[sp];
    aw += b2f(c4.w) * wgt[sp];
  }
  union { bf16 h4[4]; short4 s4; } u;
  u.h4[0] = __float2bfloat16(ax * inv);
  u.h4[1] = __float2bfloat16(ay * inv);
  u.h4[2] = __float2bfloat16(az * inv);
  u.h4[3] = __float2bfloat16(aw * inv);
  ((short4*)ctx)[i] = u.s4;
}

// ---------------- launcher ----------------
extern "C" void kernel_launch(void* const* d_in, const int* in_sizes, int n_in,
                              void* d_out, int out_size, void* d_ws, size_t ws_size,
                              hipStream_t stream) {
  const float* x = (const float*)d_in[0];
  const float* Wq = (const float*)d_in[1];
  const float* Wk = (const float*)d_in[2];
  const float* Wv = (const float*)d_in[3];
  const float* bq = (const float*)d_in[4];
  const float* bk = (const float*)d_in[5];
  const float* bv = (const float*)d_in[6];
  const float* Wo = (const float*)d_in[7];
  const float* bo = (const float*)d_in[8];
  float* outp = (float*)d_out;

  char* ws = (char*)d_ws;
  bf16* xb = (bf16*)ws;   ws += (size_t)SEQ * HIDDEN * 2;
  bf16* Wt = (bf16*)ws;   ws += (size_t)3 * HIDDEN * HIDDEN * 2;
  bf16* Wot = (bf16*)ws;  ws += (size_t)HIDDEN * HIDDEN * 2;
  bf16* Qb = (bf16*)ws;   ws += (size_t)SEQ * HIDDEN * 2;
  bf16* Kb = (bf16*)ws;   ws += (size_t)SEQ * HIDDEN * 2;
  bf16* Vt = (bf16*)ws;   ws += (size_t)SEQ * HIDDEN * 2;
  bf16* ctx = (bf16*)ws;  ws += (size_t)SEQ * HIDDEN * 2;
  bf16* partC = (bf16*)ws;  ws += (size_t)NSPLIT * SEQ * HIDDEN * 2;
  float* partM = (float*)ws; ws += (size_t)NSPLIT * HEADS * SEQ * 4;
  float* partL = (float*)ws; ws += (size_t)NSPLIT * HEADS * SEQ * 4;

  prep_kernel<<<3648, 256, 0, stream>>>(x, Wq, Wk, Wv, Wo, xb, Wt, Wot);

  gemm_kernel<0><<<32 * 18, 256, 0, stream>>>(xb, Wt, SEQ, 2304, 768, 18,
                                              bq, bk, bv, Qb, Kb, Vt, nullptr, nullptr);

  flash_kernel<<<dim3(SEQ / 128, HEADS, NSPLIT), 512, 0, stream>>>(Qb, Kb, Vt,
                                                                   partC, partM, partL);
  combine_kernel<<<SEQ * HIDDEN / 4 / 256, 256, 0, stream>>>(partC, partM, partL, ctx);

  gemm_kernel<1><<<32 * 6, 256, 0, stream>>>(ctx, Wot, SEQ, 768, 768, 6,
                                             nullptr, nullptr, nullptr, nullptr, nullptr,
                                             nullptr, bo, outp);
}